// Round 1
// baseline (5270.909 us; speedup 1.0000x reference)
//
#include <hip/hip_runtime.h>

// Problem constants
#define KC 1024          // num codes
#define DD 256           // embedding dim
#define NP 131072        // B*H*W points
#define HWSZ 4096        // H*W
#define TOTZ 33554432    // B*D*H*W

// d_out float offsets (tuple concat: quantized, loss, indices, cluster_size, ema_emb)
#define OUT_Q    0
#define OUT_LOSS 33554432
#define OUT_IDX  33554433
#define OUT_CS   33685505
#define OUT_EMA  33686529

// workspace float offsets
#define WS_IDX    0         // int[131072]
#define WS_DW     131072    // float[262144]
#define WS_COUNTS 393216    // float[1024]
#define WS_LOSSP  394240    // float[32768]
#define WS_ENORM  427008    // float[1024]

__global__ __launch_bounds__(256) void enorm_kernel(const float* __restrict__ emb,
                                                    float* __restrict__ enorm) {
    const int k = blockIdx.x;          // 1024 blocks
    const int d = threadIdx.x;         // 256 threads
    float v = emb[k * DD + d];
    v *= v;
    #pragma unroll
    for (int off = 32; off > 0; off >>= 1) v += __shfl_down(v, off);
    __shared__ float red[4];
    if ((threadIdx.x & 63) == 0) red[threadIdx.x >> 6] = v;
    __syncthreads();
    if (threadIdx.x == 0) enorm[k] = (red[0] + red[1]) + (red[2] + red[3]);
}

// 128 points x 1024 codes per block; fp32 tile GEMM + fused argmin.
__global__ __launch_bounds__(256) void dist_argmin_kernel(
    const float* __restrict__ z, const float* __restrict__ emb,
    const float* __restrict__ enorm, int* __restrict__ idx_out,
    float* __restrict__ idx_out_f, float* __restrict__ counts)
{
    __shared__ float smem[4096];           // As[8][128] | Bs[8][128], reused for reduce
    float* As = smem;
    float* Bs = smem + 1024;

    const int tid = threadIdx.x;
    const int tx = tid & 15;               // code group (8 codes each)
    const int ty = tid >> 4;               // row group  (8 points each)
    const int p0 = blockIdx.x * 128;
    const int b  = p0 >> 12;
    const int hw0 = p0 & 4095;
    const float* zb = z + (size_t)b * (DD * HWSZ) + hw0;   // + d*4096 + row

    const int arow = (tid & 31) * 4;       // A staging: 32 float4 rows x 8 kd
    const int akd  = tid >> 5;
    const int bcode = tid >> 1;            // B staging: 128 codes x 2 float4
    const int bj    = (tid & 1) * 4;

    float best[8];
    int   bidx[8];
    #pragma unroll
    for (int i = 0; i < 8; i++) { best[i] = 3.4e38f; bidx[i] = 0; }

    #pragma unroll 1
    for (int cc = 0; cc < 8; ++cc) {
        const int c0 = cc * 128;
        float acc[8][8];
        #pragma unroll
        for (int i = 0; i < 8; i++)
            #pragma unroll
            for (int j = 0; j < 8; j++) acc[i][j] = 0.0f;

        #pragma unroll 1
        for (int dk = 0; dk < 32; ++dk) {
            const int kk0 = dk * 8;
            const float4 av = *(const float4*)(zb + (kk0 + akd) * HWSZ + arow);
            const float4 bv = *(const float4*)(emb + (c0 + bcode) * DD + kk0 + bj);
            __syncthreads();
            *(float4*)(As + akd * 128 + arow) = av;
            Bs[(bj + 0) * 128 + bcode] = bv.x;
            Bs[(bj + 1) * 128 + bcode] = bv.y;
            Bs[(bj + 2) * 128 + bcode] = bv.z;
            Bs[(bj + 3) * 128 + bcode] = bv.w;
            __syncthreads();
            #pragma unroll
            for (int kk = 0; kk < 8; ++kk) {
                const float4 a0 = *(const float4*)(As + kk * 128 + ty * 8);
                const float4 a1 = *(const float4*)(As + kk * 128 + ty * 8 + 4);
                const float4 b0 = *(const float4*)(Bs + kk * 128 + tx * 8);
                const float4 b1 = *(const float4*)(Bs + kk * 128 + tx * 8 + 4);
                const float a[8] = {a0.x,a0.y,a0.z,a0.w,a1.x,a1.y,a1.z,a1.w};
                const float bb[8] = {b0.x,b0.y,b0.z,b0.w,b1.x,b1.y,b1.z,b1.w};
                #pragma unroll
                for (int i = 0; i < 8; i++)
                    #pragma unroll
                    for (int j = 0; j < 8; j++)
                        acc[i][j] = fmaf(a[i], bb[j], acc[i][j]);
            }
        }
        // epilogue: dist = enorm - 2*dot (||z||^2 constant per point, argmin-invariant)
        const float4 en0 = *(const float4*)(enorm + c0 + tx * 8);
        const float4 en1 = *(const float4*)(enorm + c0 + tx * 8 + 4);
        const float en[8] = {en0.x,en0.y,en0.z,en0.w,en1.x,en1.y,en1.z,en1.w};
        #pragma unroll
        for (int j = 0; j < 8; j++) {
            const int c = c0 + tx * 8 + j;
            #pragma unroll
            for (int i = 0; i < 8; i++) {
                const float dist = fmaf(-2.0f, acc[i][j], en[j]);
                if (dist < best[i]) { best[i] = dist; bidx[i] = c; }
            }
        }
    }

    // cross-tx argmin reduce via LDS (prefer lower index on exact tie, numpy semantics)
    __syncthreads();
    float* rmin = smem;                 // [128][16]
    int*   ridx = (int*)(smem + 2048);  // [128][16]
    #pragma unroll
    for (int i = 0; i < 8; i++) {
        const int r = ty * 8 + i;
        rmin[r * 16 + tx] = best[i];
        ridx[r * 16 + tx] = bidx[i];
    }
    __syncthreads();
    if (tid < 128) {
        const int r = tid;
        float m = rmin[r * 16];
        int  mi = ridx[r * 16];
        #pragma unroll
        for (int t = 1; t < 16; t++) {
            const float v = rmin[r * 16 + t];
            const int  vi = ridx[r * 16 + t];
            if (v < m || (v == m && vi < mi)) { m = v; mi = vi; }
        }
        const int p = p0 + r;
        idx_out[p] = mi;
        idx_out_f[p] = (float)mi;
        atomicAdd(&counts[mi], 1.0f);
    }
}

__global__ __launch_bounds__(256) void quantize_kernel(
    const float* __restrict__ z, const float* __restrict__ emb,
    const int* __restrict__ idx, float* __restrict__ out_q,
    float* __restrict__ lossp, float* __restrict__ dw)
{
    const int t = blockIdx.x * 256 + threadIdx.x;
    const int i4 = t << 2;
    const int bd = i4 >> 12;           // b*256 + d
    const int hw = i4 & 4095;
    const int d = bd & 255;
    const int b = bd >> 8;
    const int p = (b << 12) | hw;
    const float4 zv = *(const float4*)(z + i4);
    const int4  iv = *(const int4*)(idx + p);
    const float q0 = emb[(iv.x << 8) + d];
    const float q1 = emb[(iv.y << 8) + d];
    const float q2 = emb[(iv.z << 8) + d];
    const float q3 = emb[(iv.w << 8) + d];
    float4 qv; qv.x = q0; qv.y = q1; qv.z = q2; qv.w = q3;
    *(float4*)(out_q + i4) = qv;
    atomicAdd(&dw[(iv.x << 8) + d], zv.x);
    atomicAdd(&dw[(iv.y << 8) + d], zv.y);
    atomicAdd(&dw[(iv.z << 8) + d], zv.z);
    atomicAdd(&dw[(iv.w << 8) + d], zv.w);
    const float d0 = zv.x - q0, d1 = zv.y - q1, d2 = zv.z - q2, d3 = zv.w - q3;
    float ls = (d0 * d0 + d1 * d1) + (d2 * d2 + d3 * d3);
    #pragma unroll
    for (int off = 32; off > 0; off >>= 1) ls += __shfl_down(ls, off);
    __shared__ float red[4];
    if ((threadIdx.x & 63) == 0) red[threadIdx.x >> 6] = ls;
    __syncthreads();
    if (threadIdx.x == 0) lossp[blockIdx.x] = (red[0] + red[1]) + (red[2] + red[3]);
}

__global__ __launch_bounds__(256) void finalize_kernel(
    const float* __restrict__ ema_cs, const float* __restrict__ ema_emb,
    const float* __restrict__ counts, const float* __restrict__ dw,
    const float* __restrict__ lossp, float* __restrict__ out)
{
    const int i = blockIdx.x * 256 + threadIdx.x;   // 1024 blocks * 256 = 262144 exact
    out[OUT_EMA + i] = 0.99f * ema_emb[i] + 0.01f * dw[i];
    if (i < 1024) out[OUT_CS + i] = 0.99f * ema_cs[i] + 0.01f * counts[i];
    if (blockIdx.x == 0) {
        float s = 0.0f;
        for (int t = threadIdx.x; t < 32768; t += 256) s += lossp[t];
        #pragma unroll
        for (int off = 32; off > 0; off >>= 1) s += __shfl_down(s, off);
        __shared__ float red[4];
        if ((threadIdx.x & 63) == 0) red[threadIdx.x >> 6] = s;
        __syncthreads();
        if (threadIdx.x == 0)
            out[OUT_LOSS] = 0.25f * ((red[0] + red[1]) + (red[2] + red[3])) / 33554432.0f;
    }
}

extern "C" void kernel_launch(void* const* d_in, const int* in_sizes, int n_in,
                              void* d_out, int out_size, void* d_ws, size_t ws_size,
                              hipStream_t stream) {
    const float* z       = (const float*)d_in[0];
    const float* emb     = (const float*)d_in[1];
    const float* ema_cs  = (const float*)d_in[2];
    const float* ema_emb = (const float*)d_in[3];
    float* out = (float*)d_out;
    float* ws  = (float*)d_ws;

    int*   ws_idx    = (int*)(ws + WS_IDX);
    float* ws_dw     = ws + WS_DW;
    float* ws_counts = ws + WS_COUNTS;
    float* ws_lossp  = ws + WS_LOSSP;
    float* ws_enorm  = ws + WS_ENORM;

    // zero dw + counts (ws is poisoned 0xAA each call)
    hipMemsetAsync(ws_dw, 0, (WS_LOSSP - WS_DW) * sizeof(float), stream);

    hipLaunchKernelGGL(enorm_kernel, dim3(KC), dim3(256), 0, stream, emb, ws_enorm);
    hipLaunchKernelGGL(dist_argmin_kernel, dim3(NP / 128), dim3(256), 0, stream,
                       z, emb, ws_enorm, ws_idx, out + OUT_IDX, ws_counts);
    hipLaunchKernelGGL(quantize_kernel, dim3(TOTZ / 1024), dim3(256), 0, stream,
                       z, emb, ws_idx, out, ws_lossp, ws_dw);
    hipLaunchKernelGGL(finalize_kernel, dim3(262144 / 256), dim3(256), 0, stream,
                       ema_cs, ema_emb, ws_counts, ws_dw, ws_lossp, out);
}

// Round 2
// 1331.305 us; speedup vs baseline: 3.9592x; 3.9592x over previous
//
#include <hip/hip_runtime.h>

// Problem constants
#define KC 1024          // num codes
#define DD 256           // embedding dim
#define NP 131072        // B*H*W points
#define HWSZ 4096        // H*W
#define TOTZ 33554432    // B*D*H*W

// d_out float offsets (tuple concat: quantized, loss, indices, cluster_size, ema_emb)
#define OUT_Q    0
#define OUT_LOSS 33554432
#define OUT_IDX  33554433
#define OUT_CS   33685505
#define OUT_EMA  33686529

// workspace float offsets
#define WS_IDX    0         // int[131072]
#define WS_COUNTS 131072    // float[1024]
#define WS_LOSSP  132096    // float[32768]
#define WS_ENORM  164864    // float[1024]

__global__ __launch_bounds__(256) void enorm_kernel(const float* __restrict__ emb,
                                                    float* __restrict__ enorm) {
    const int k = blockIdx.x;          // 1024 blocks
    const int d = threadIdx.x;         // 256 threads
    float v = emb[k * DD + d];
    v *= v;
    #pragma unroll
    for (int off = 32; off > 0; off >>= 1) v += __shfl_down(v, off);
    __shared__ float red[4];
    if ((threadIdx.x & 63) == 0) red[threadIdx.x >> 6] = v;
    __syncthreads();
    if (threadIdx.x == 0) enorm[k] = (red[0] + red[1]) + (red[2] + red[3]);
}

// 128 points x 1024 codes per block; fp32 tile GEMM + fused argmin.
__global__ __launch_bounds__(256) void dist_argmin_kernel(
    const float* __restrict__ z, const float* __restrict__ emb,
    const float* __restrict__ enorm, int* __restrict__ idx_out,
    float* __restrict__ idx_out_f, float* __restrict__ counts)
{
    __shared__ float smem[4096];           // As[8][128] | Bs[8][128], reused for reduce
    float* As = smem;
    float* Bs = smem + 1024;

    const int tid = threadIdx.x;
    const int tx = tid & 15;               // code group (8 codes each)
    const int ty = tid >> 4;               // row group  (8 points each)
    const int p0 = blockIdx.x * 128;
    const int b  = p0 >> 12;
    const int hw0 = p0 & 4095;
    const float* zb = z + (size_t)b * (DD * HWSZ) + hw0;   // + d*4096 + row

    const int arow = (tid & 31) * 4;       // A staging: 32 float4 rows x 8 kd
    const int akd  = tid >> 5;
    const int bcode = tid >> 1;            // B staging: 128 codes x 2 float4
    const int bj    = (tid & 1) * 4;

    float best[8];
    int   bidx[8];
    #pragma unroll
    for (int i = 0; i < 8; i++) { best[i] = 3.4e38f; bidx[i] = 0; }

    #pragma unroll 1
    for (int cc = 0; cc < 8; ++cc) {
        const int c0 = cc * 128;
        float acc[8][8];
        #pragma unroll
        for (int i = 0; i < 8; i++)
            #pragma unroll
            for (int j = 0; j < 8; j++) acc[i][j] = 0.0f;

        #pragma unroll 1
        for (int dk = 0; dk < 32; ++dk) {
            const int kk0 = dk * 8;
            const float4 av = *(const float4*)(zb + (kk0 + akd) * HWSZ + arow);
            const float4 bv = *(const float4*)(emb + (c0 + bcode) * DD + kk0 + bj);
            __syncthreads();
            *(float4*)(As + akd * 128 + arow) = av;
            Bs[(bj + 0) * 128 + bcode] = bv.x;
            Bs[(bj + 1) * 128 + bcode] = bv.y;
            Bs[(bj + 2) * 128 + bcode] = bv.z;
            Bs[(bj + 3) * 128 + bcode] = bv.w;
            __syncthreads();
            #pragma unroll
            for (int kk = 0; kk < 8; ++kk) {
                const float4 a0 = *(const float4*)(As + kk * 128 + ty * 8);
                const float4 a1 = *(const float4*)(As + kk * 128 + ty * 8 + 4);
                const float4 b0 = *(const float4*)(Bs + kk * 128 + tx * 8);
                const float4 b1 = *(const float4*)(Bs + kk * 128 + tx * 8 + 4);
                const float a[8] = {a0.x,a0.y,a0.z,a0.w,a1.x,a1.y,a1.z,a1.w};
                const float bb[8] = {b0.x,b0.y,b0.z,b0.w,b1.x,b1.y,b1.z,b1.w};
                #pragma unroll
                for (int i = 0; i < 8; i++)
                    #pragma unroll
                    for (int j = 0; j < 8; j++)
                        acc[i][j] = fmaf(a[i], bb[j], acc[i][j]);
            }
        }
        // epilogue: dist = enorm - 2*dot (||z||^2 constant per point, argmin-invariant)
        const float4 en0 = *(const float4*)(enorm + c0 + tx * 8);
        const float4 en1 = *(const float4*)(enorm + c0 + tx * 8 + 4);
        const float en[8] = {en0.x,en0.y,en0.z,en0.w,en1.x,en1.y,en1.z,en1.w};
        #pragma unroll
        for (int j = 0; j < 8; j++) {
            const int c = c0 + tx * 8 + j;
            #pragma unroll
            for (int i = 0; i < 8; i++) {
                const float dist = fmaf(-2.0f, acc[i][j], en[j]);
                if (dist < best[i]) { best[i] = dist; bidx[i] = c; }
            }
        }
    }

    // cross-tx argmin reduce via LDS (prefer lower index on exact tie, numpy semantics)
    __syncthreads();
    float* rmin = smem;                 // [128][16]
    int*   ridx = (int*)(smem + 2048);  // [128][16]
    #pragma unroll
    for (int i = 0; i < 8; i++) {
        const int r = ty * 8 + i;
        rmin[r * 16 + tx] = best[i];
        ridx[r * 16 + tx] = bidx[i];
    }
    __syncthreads();
    if (tid < 128) {
        const int r = tid;
        float m = rmin[r * 16];
        int  mi = ridx[r * 16];
        #pragma unroll
        for (int t = 1; t < 16; t++) {
            const float v = rmin[r * 16 + t];
            const int  vi = ridx[r * 16 + t];
            if (v < m || (v == m && vi < mi)) { m = v; mi = vi; }
        }
        const int p = p0 + r;
        idx_out[p] = mi;
        idx_out_f[p] = (float)mi;
        atomicAdd(&counts[mi], 1.0f);
    }
}

// Pure streaming: quantized gather + loss partials. No atomics.
__global__ __launch_bounds__(256) void quantize_kernel(
    const float* __restrict__ z, const float* __restrict__ emb,
    const int* __restrict__ idx, float* __restrict__ out_q,
    float* __restrict__ lossp)
{
    const int t = blockIdx.x * 256 + threadIdx.x;
    const int i4 = t << 2;
    const int bd = i4 >> 12;           // b*256 + d
    const int hw = i4 & 4095;
    const int d = bd & 255;
    const int b = bd >> 8;
    const int p = (b << 12) | hw;
    const float4 zv = *(const float4*)(z + i4);
    const int4  iv = *(const int4*)(idx + p);
    const float q0 = emb[(iv.x << 8) + d];
    const float q1 = emb[(iv.y << 8) + d];
    const float q2 = emb[(iv.z << 8) + d];
    const float q3 = emb[(iv.w << 8) + d];
    float4 qv; qv.x = q0; qv.y = q1; qv.z = q2; qv.w = q3;
    *(float4*)(out_q + i4) = qv;
    const float d0 = zv.x - q0, d1 = zv.y - q1, d2 = zv.z - q2, d3 = zv.w - q3;
    float ls = (d0 * d0 + d1 * d1) + (d2 * d2 + d3 * d3);
    #pragma unroll
    for (int off = 32; off > 0; off >>= 1) ls += __shfl_down(ls, off);
    __shared__ float red[4];
    if ((threadIdx.x & 63) == 0) red[threadIdx.x >> 6] = ls;
    __syncthreads();
    if (threadIdx.x == 0) lossp[blockIdx.x] = (red[0] + red[1]) + (red[2] + red[3]);
}

// LDS-privatized segment sum: block = one dim d; kdw[k] accumulates over all
// points via LDS atomics; fused EMA-embedding write (each (k,d) owned by one
// thread -> zero global atomics).
__global__ __launch_bounds__(256) void dw_kernel(
    const float* __restrict__ z, const int* __restrict__ idx,
    const float* __restrict__ ema_emb, float* __restrict__ out_ema)
{
    __shared__ float kdw[KC];
    #pragma unroll
    for (int k = threadIdx.x; k < KC; k += 256) kdw[k] = 0.0f;
    __syncthreads();
    const int d = blockIdx.x;
    #pragma unroll 1
    for (int b = 0; b < 32; ++b) {
        const float* zp = z + (size_t)b * (DD * HWSZ) + (size_t)d * HWSZ;
        const int*   ip = idx + b * HWSZ;
        #pragma unroll
        for (int it = 0; it < 4; ++it) {
            const int hw = (it * 256 + threadIdx.x) * 4;
            const float4 zv = *(const float4*)(zp + hw);
            const int4   iv = *(const int4*)(ip + hw);
            atomicAdd(&kdw[iv.x], zv.x);
            atomicAdd(&kdw[iv.y], zv.y);
            atomicAdd(&kdw[iv.z], zv.z);
            atomicAdd(&kdw[iv.w], zv.w);
        }
    }
    __syncthreads();
    for (int k = threadIdx.x; k < KC; k += 256)
        out_ema[k * DD + d] = 0.99f * ema_emb[k * DD + d] + 0.01f * kdw[k];
}

__global__ __launch_bounds__(256) void finalize_kernel(
    const float* __restrict__ ema_cs, const float* __restrict__ counts,
    const float* __restrict__ lossp, float* __restrict__ out)
{
    const int i = blockIdx.x * 256 + threadIdx.x;   // 4 blocks * 256 = 1024
    out[OUT_CS + i] = 0.99f * ema_cs[i] + 0.01f * counts[i];
    if (blockIdx.x == 0) {
        float s = 0.0f;
        for (int t = threadIdx.x; t < 32768; t += 256) s += lossp[t];
        #pragma unroll
        for (int off = 32; off > 0; off >>= 1) s += __shfl_down(s, off);
        __shared__ float red[4];
        if ((threadIdx.x & 63) == 0) red[threadIdx.x >> 6] = s;
        __syncthreads();
        if (threadIdx.x == 0)
            out[OUT_LOSS] = 0.25f * ((red[0] + red[1]) + (red[2] + red[3])) / 33554432.0f;
    }
}

extern "C" void kernel_launch(void* const* d_in, const int* in_sizes, int n_in,
                              void* d_out, int out_size, void* d_ws, size_t ws_size,
                              hipStream_t stream) {
    const float* z       = (const float*)d_in[0];
    const float* emb     = (const float*)d_in[1];
    const float* ema_cs  = (const float*)d_in[2];
    const float* ema_emb = (const float*)d_in[3];
    float* out = (float*)d_out;
    float* ws  = (float*)d_ws;

    int*   ws_idx    = (int*)(ws + WS_IDX);
    float* ws_counts = ws + WS_COUNTS;
    float* ws_lossp  = ws + WS_LOSSP;
    float* ws_enorm  = ws + WS_ENORM;

    // zero counts (ws is poisoned 0xAA each call)
    hipMemsetAsync(ws_counts, 0, KC * sizeof(float), stream);

    hipLaunchKernelGGL(enorm_kernel, dim3(KC), dim3(256), 0, stream, emb, ws_enorm);
    hipLaunchKernelGGL(dist_argmin_kernel, dim3(NP / 128), dim3(256), 0, stream,
                       z, emb, ws_enorm, ws_idx, out + OUT_IDX, ws_counts);
    hipLaunchKernelGGL(quantize_kernel, dim3(TOTZ / 1024), dim3(256), 0, stream,
                       z, emb, ws_idx, out, ws_lossp);
    hipLaunchKernelGGL(dw_kernel, dim3(DD), dim3(256), 0, stream,
                       z, ws_idx, ema_emb, out + OUT_EMA);
    hipLaunchKernelGGL(finalize_kernel, dim3(4), dim3(256), 0, stream,
                       ema_cs, ws_counts, ws_lossp, out);
}

// Round 3
// 1210.405 us; speedup vs baseline: 4.3547x; 1.0999x over previous
//
#include <hip/hip_runtime.h>

// Problem constants
#define KC 1024          // num codes
#define DD 256           // embedding dim
#define NP 131072        // B*H*W points
#define HWSZ 4096        // H*W
#define TOTZ 33554432    // B*D*H*W

// d_out float offsets (tuple concat: quantized, loss, indices, cluster_size, ema_emb)
#define OUT_Q    0
#define OUT_LOSS 33554432
#define OUT_IDX  33554433
#define OUT_CS   33685505
#define OUT_EMA  33686529

// workspace float offsets
#define WS_IDX    0         // int[131072]
#define WS_COUNTS 131072    // float[1024]
#define WS_RCNT   132096    // int[1]  (memset together with counts: 1025 floats)
#define WS_LOSSP  132352    // float[256]
#define WS_ENORM  132608    // float[1024]
#define WS_RLIST  133632    // int[131072]
#define WS_EAUG   264704    // ushort[786432] = 393216 floats (8 cc x 12 ks x 16KB)
#define WS_ZAUG   657920    // ushort[67108864] = 33554432 floats (1024 pt x 8 ksA x 16KB)
#define WS_NEED_FLOATS (WS_ZAUG + 33554432)

#define MARGIN 0.125f

typedef __attribute__((ext_vector_type(8))) short bf16x8;
typedef __attribute__((ext_vector_type(4))) float f32x4;

__device__ inline unsigned short f2bf_rne(float x) {
    unsigned u = __float_as_uint(x);
    unsigned r = u + 0x7FFFu + ((u >> 16) & 1u);
    return (unsigned short)(r >> 16);
}
__device__ inline float bf2f(unsigned short h) {
    return __uint_as_float(((unsigned)h) << 16);
}
__device__ inline void gl_lds16(const void* g, void* l) {
    __builtin_amdgcn_global_load_lds(
        (const __attribute__((address_space(1))) unsigned int*)g,
        (__attribute__((address_space(3))) unsigned int*)l, 16, 0, 0);
}

__global__ __launch_bounds__(256) void enorm_kernel(const float* __restrict__ emb,
                                                    float* __restrict__ enorm) {
    const int k = blockIdx.x;
    float v = emb[k * DD + threadIdx.x];
    v *= v;
    #pragma unroll
    for (int off = 32; off > 0; off >>= 1) v += __shfl_down(v, off);
    __shared__ float red[4];
    if ((threadIdx.x & 63) == 0) red[threadIdx.x >> 6] = v;
    __syncthreads();
    if (threadIdx.x == 0) enorm[k] = (red[0] + red[1]) + (red[2] + red[3]);
}

// z_aug: [pt(1024)][ksA(8)][kc(2)][mt(8)][lane(64)][8 bf16]
// ksA 0..3 = hi(k = ksA*64 + ...), ksA 4..7 = mid.  (GEMM maps ks 8..11 -> phys 0..3)
__global__ __launch_bounds__(256) void convert_z_kernel(
    const float* __restrict__ z, unsigned short* __restrict__ zaug)
{
    const int blk = blockIdx.x;            // pt*8 + ksA
    const int pt = blk >> 3, ksA = blk & 7;
    const int mode = ksA >> 2;             // 0 hi, 1 mid
    const int kbase0 = (ksA & 3) * 64;
    unsigned short* outp = zaug + (size_t)blk * 8192;
    #pragma unroll
    for (int i = 0; i < 4; ++i) {
        const int f = i * 256 + threadIdx.x;   // fragment index [0,1024)
        const int kc = f >> 9, mt = (f >> 6) & 7, lane = f & 63;
        const int q = lane >> 4, col = lane & 15;
        const int p = pt * 128 + mt * 16 + col;
        const int b = p >> 12, hw = p & 4095;
        const int k0 = kbase0 + kc * 32 + q * 8;
        const float* src = z + (size_t)b * 1048576 + (size_t)k0 * 4096 + hw;
        unsigned short v[8];
        #pragma unroll
        for (int j = 0; j < 8; ++j) {
            const float x = src[j * 4096];
            const unsigned short h = f2bf_rne(x);
            v[j] = mode ? f2bf_rne(x - bf2f(h)) : h;
        }
        *(uint4*)(outp + (size_t)f * 8) = *(uint4*)v;
    }
}

// emb_aug: [cc(8)][ks(12)][kc(2)][nt(8)][lane(64)][8 bf16]; ks 0..7 = hi, 8..11 = mid
__global__ __launch_bounds__(256) void convert_emb_kernel(
    const float* __restrict__ emb, unsigned short* __restrict__ eaug)
{
    const int blk = blockIdx.x;            // cc*12 + ks
    const int cc = blk / 12, ks = blk % 12;
    const int mode = (ks >= 8);
    unsigned short* outp = eaug + (size_t)blk * 8192;
    #pragma unroll
    for (int i = 0; i < 4; ++i) {
        const int f = i * 256 + threadIdx.x;
        const int kc = f >> 9, nt = (f >> 6) & 7, lane = f & 63;
        const int q = lane >> 4, col = lane & 15;
        const int n = cc * 128 + nt * 16 + col;
        const int k0 = ((ks * 64) & 255) + kc * 32 + q * 8;
        const float* src = emb + (size_t)n * 256 + k0;
        unsigned short v[8];
        #pragma unroll
        for (int j = 0; j < 8; ++j) {
            const float x = src[j];
            const unsigned short h = f2bf_rne(x);
            v[j] = mode ? f2bf_rne(x - bf2f(h)) : h;
        }
        *(uint4*)(outp + (size_t)f * 8) = *(uint4*)v;
    }
}

// MFMA GEMM + fused argmin. Block: 128 points x (8 cc chunks of 128 codes).
// 4 waves, each 64x64 quadrant (mh = w&1, nh = w>>1).
__global__ __launch_bounds__(256) void gemm_argmin_kernel(
    const unsigned short* __restrict__ zaug, const unsigned short* __restrict__ eaug,
    const float* __restrict__ enorm, int* __restrict__ idx_out,
    float* __restrict__ idx_out_f, float* __restrict__ counts,
    int* __restrict__ rcnt, int* __restrict__ rlist)
{
    __shared__ float smem[12288];                      // 48 KB
    unsigned short* aS = (unsigned short*)smem;        // 8192 hw (16 KB)
    unsigned short* bS = (unsigned short*)(smem + 4096);
    const int t = threadIdx.x, w = t >> 6, lane = t & 63;
    const int mh = w & 1, nh = w >> 1;
    const int pt = blockIdx.x;

    float rb[16], rs[16]; int ri[16];
    #pragma unroll
    for (int s = 0; s < 16; ++s) { rb[s] = 3.4e38f; rs[s] = 3.4e38f; ri[s] = 0; }

    #pragma unroll 1
    for (int cc = 0; cc < 8; ++cc) {
        f32x4 acc[4][4];
        #pragma unroll
        for (int mi = 0; mi < 4; ++mi)
            #pragma unroll
            for (int ni = 0; ni < 4; ++ni) acc[mi][ni] = (f32x4){0.f, 0.f, 0.f, 0.f};

        float en[4];
        #pragma unroll
        for (int ni = 0; ni < 4; ++ni)
            en[ni] = enorm[cc * 128 + nh * 64 + ni * 16 + (lane & 15)];

        #pragma unroll 1
        for (int ks = 0; ks < 12; ++ks) {
            const int ksA = (ks < 8) ? ks : (ks - 8);
            const unsigned short* ga = zaug + ((size_t)(pt * 8 + ksA)) * 8192;
            const unsigned short* gb = eaug + ((size_t)(cc * 12 + ks)) * 8192;
            #pragma unroll
            for (int i = 0; i < 4; ++i) {
                const int off = i * 2048 + w * 512 + lane * 8;   // halfwords
                gl_lds16(ga + off, aS + off);
                gl_lds16(gb + off, bS + off);
            }
            __syncthreads();
            #pragma unroll
            for (int kc = 0; kc < 2; ++kc) {
                bf16x8 af[4], bf[4];
                #pragma unroll
                for (int mi = 0; mi < 4; ++mi)
                    af[mi] = *(const bf16x8*)(aS + kc * 4096 + (mh * 4 + mi) * 512 + lane * 8);
                #pragma unroll
                for (int ni = 0; ni < 4; ++ni)
                    bf[ni] = *(const bf16x8*)(bS + kc * 4096 + (nh * 4 + ni) * 512 + lane * 8);
                #pragma unroll
                for (int mi = 0; mi < 4; ++mi)
                    #pragma unroll
                    for (int ni = 0; ni < 4; ++ni)
                        acc[mi][ni] = __builtin_amdgcn_mfma_f32_16x16x32_bf16(
                            af[mi], bf[ni], acc[mi][ni], 0, 0, 0);
            }
            __syncthreads();
        }
        // epilogue: dist = enorm - 2*dot; per-slot (min, 2nd, idx) over 4 nt, merge
        #pragma unroll
        for (int mi = 0; mi < 4; ++mi) {
            #pragma unroll
            for (int r = 0; r < 4; ++r) {
                const int s = mi * 4 + r;
                float v0 = fmaf(-2.f, acc[mi][0][r], en[0]);
                float v1 = fmaf(-2.f, acc[mi][1][r], en[1]);
                float v2 = fmaf(-2.f, acc[mi][2][r], en[2]);
                float v3 = fmaf(-2.f, acc[mi][3][r], en[3]);
                const int nb = cc * 128 + nh * 64 + (lane & 15);
                float b01 = fminf(v0, v1), x01 = fmaxf(v0, v1);
                int   i01 = (v1 < v0) ? nb + 16 : nb;
                float b23 = fminf(v2, v3), x23 = fmaxf(v2, v3);
                int   i23 = (v3 < v2) ? nb + 48 : nb + 32;
                float b = fminf(b01, b23);
                int   ib = (b23 < b01) ? i23 : i01;
                float s2 = fminf(fmaxf(b01, b23), fminf(x01, x23));
                if (b < rb[s]) { rs[s] = fminf(rb[s], s2); rb[s] = b; ri[s] = ib; }
                else           { rs[s] = fminf(rs[s], b); }
            }
        }
    }

    // dump per-lane running state to LDS, then threads 0..127 finalize one point each
    #pragma unroll
    for (int s = 0; s < 16; ++s) {
        smem[w * 1024 + s * 64 + lane] = rb[s];
        smem[4096 + w * 1024 + s * 64 + lane] = rs[s];
        ((int*)smem)[8192 + w * 1024 + s * 64 + lane] = ri[s];
    }
    __syncthreads();
    if (t < 128) {
        const int mi = (t >> 4) & 3, q = (t >> 2) & 3, r = t & 3;
        const int s = mi * 4 + r;
        float B = 3.4e38f, S = 3.4e38f; int I = 0;
        #pragma unroll
        for (int h = 0; h < 2; ++h) {
            const int wv = (t >> 6) + h * 2;
            const int base = wv * 1024 + s * 64 + q * 16;
            #pragma unroll
            for (int ln = 0; ln < 16; ++ln) {
                const float b = smem[base + ln];
                const float s2 = smem[4096 + base + ln];
                const int   i = ((int*)smem)[8192 + base + ln];
                if (b < B) { S = fminf(B, s2); B = b; I = i; }
                else       { S = fminf(S, b); }
            }
        }
        const int p = pt * 128 + t;
        idx_out[p] = I;
        idx_out_f[p] = (float)I;
        atomicAdd(&counts[I], 1.0f);
        if (S - B < MARGIN) {
            const int pos = atomicAdd(rcnt, 1);
            rlist[pos] = p;
        }
    }
}

// Exact fp32 re-argmin for flagged points; fixes idx/counts.
__global__ __launch_bounds__(256) void rescue_kernel(
    const float* __restrict__ z, const float* __restrict__ emb,
    const float* __restrict__ enorm, const int* __restrict__ rcnt,
    const int* __restrict__ rlist, int* __restrict__ idx_out,
    float* __restrict__ idx_out_f, float* __restrict__ counts)
{
    __shared__ float zl[DD];
    __shared__ float rbd[4]; __shared__ int rbc[4];
    const int n = *rcnt;
    const int t = threadIdx.x;
    for (int ridx = blockIdx.x; ridx < n; ridx += gridDim.x) {
        const int p = rlist[ridx];
        const int b = p >> 12, hw = p & 4095;
        zl[t] = z[(size_t)b * 1048576 + (size_t)t * 4096 + hw];
        __syncthreads();
        float bd = 3.4e38f; int bc = 0;
        #pragma unroll 1
        for (int ci = 0; ci < 4; ++ci) {
            const int c = ci * 256 + t;
            const float* e = emb + (size_t)c * 256;
            float dot = 0.f;
            #pragma unroll
            for (int d = 0; d < 256; d += 4) {
                const float4 ev = *(const float4*)(e + d);
                const float4 zv = *(const float4*)(zl + d);
                dot = fmaf(zv.x, ev.x, dot); dot = fmaf(zv.y, ev.y, dot);
                dot = fmaf(zv.z, ev.z, dot); dot = fmaf(zv.w, ev.w, dot);
            }
            const float dist = fmaf(-2.f, dot, enorm[c]);
            if (dist < bd || (dist == bd && c < bc)) { bd = dist; bc = c; }
        }
        #pragma unroll
        for (int off = 32; off > 0; off >>= 1) {
            const float od = __shfl_down(bd, off);
            const int   oc = __shfl_down(bc, off);
            if (od < bd || (od == bd && oc < bc)) { bd = od; bc = oc; }
        }
        if ((t & 63) == 0) { rbd[t >> 6] = bd; rbc[t >> 6] = bc; }
        __syncthreads();
        if (t == 0) {
            float fb = rbd[0]; int fc = rbc[0];
            #pragma unroll
            for (int i = 1; i < 4; ++i)
                if (rbd[i] < fb || (rbd[i] == fb && rbc[i] < fc)) { fb = rbd[i]; fc = rbc[i]; }
            const int old = idx_out[p];
            if (fc != old) {
                atomicAdd(&counts[old], -1.0f);
                atomicAdd(&counts[fc], 1.0f);
                idx_out[p] = fc;
                idx_out_f[p] = (float)fc;
            }
        }
        __syncthreads();
    }
}

// Fused quantize + dw-segment-sum + loss. Block = one dim d (256 blocks x 512 thr).
// emb column d staged in LDS -> gather becomes LDS read; dw privatized in LDS;
// fused EMA-embedding write (each (k,d) owned by this block).
__global__ __launch_bounds__(512) void dwq_kernel(
    const float* __restrict__ z, const float* __restrict__ emb,
    const int* __restrict__ idx, const float* __restrict__ ema_emb,
    float* __restrict__ out_q, float* __restrict__ out_ema,
    float* __restrict__ lossp)
{
    __shared__ float kdw[KC];
    __shared__ float ecol[KC];
    __shared__ float red[8];
    const int d = blockIdx.x;
    const int t = threadIdx.x;
    #pragma unroll
    for (int k = t; k < KC; k += 512) { kdw[k] = 0.f; ecol[k] = emb[(size_t)k * 256 + d]; }
    __syncthreads();
    float ls = 0.f;
    #pragma unroll 1
    for (int it = 0; it < 64; ++it) {
        const int e = it * 512 + t;            // float4-unit over (b, hw)
        const int b = e >> 10, hwi = (e & 1023) << 2;
        const size_t zoff = (size_t)b * 1048576 + (size_t)d * 4096 + hwi;
        const float4 zv = *(const float4*)(z + zoff);
        const int4 iv = *(const int4*)(idx + b * 4096 + hwi);
        const float q0 = ecol[iv.x], q1 = ecol[iv.y], q2 = ecol[iv.z], q3 = ecol[iv.w];
        float4 qv; qv.x = q0; qv.y = q1; qv.z = q2; qv.w = q3;
        *(float4*)(out_q + zoff) = qv;
        atomicAdd(&kdw[iv.x], zv.x);
        atomicAdd(&kdw[iv.y], zv.y);
        atomicAdd(&kdw[iv.z], zv.z);
        atomicAdd(&kdw[iv.w], zv.w);
        const float d0 = zv.x - q0, d1 = zv.y - q1, d2 = zv.z - q2, d3 = zv.w - q3;
        ls += (d0 * d0 + d1 * d1) + (d2 * d2 + d3 * d3);
    }
    __syncthreads();
    #pragma unroll
    for (int k = t; k < KC; k += 512)
        out_ema[(size_t)k * 256 + d] = 0.99f * ema_emb[(size_t)k * 256 + d] + 0.01f * kdw[k];
    #pragma unroll
    for (int off = 32; off > 0; off >>= 1) ls += __shfl_down(ls, off);
    if ((t & 63) == 0) red[t >> 6] = ls;
    __syncthreads();
    if (t == 0) {
        float s = 0.f;
        #pragma unroll
        for (int i = 0; i < 8; ++i) s += red[i];
        lossp[blockIdx.x] = s;
    }
}

__global__ __launch_bounds__(256) void finalize_kernel(
    const float* __restrict__ ema_cs, const float* __restrict__ counts,
    const float* __restrict__ lossp, float* __restrict__ out)
{
    const int i = blockIdx.x * 256 + threadIdx.x;   // 4 blocks
    out[OUT_CS + i] = 0.99f * ema_cs[i] + 0.01f * counts[i];
    if (blockIdx.x == 0) {
        float s = lossp[threadIdx.x];
        #pragma unroll
        for (int off = 32; off > 0; off >>= 1) s += __shfl_down(s, off);
        __shared__ float red[4];
        if ((threadIdx.x & 63) == 0) red[threadIdx.x >> 6] = s;
        __syncthreads();
        if (threadIdx.x == 0)
            out[OUT_LOSS] = 0.25f * ((red[0] + red[1]) + (red[2] + red[3])) / 33554432.0f;
    }
}

// ---------- fallback fp32 GEMM (R2 path, used if ws too small) ----------
__global__ __launch_bounds__(256) void dist_argmin_kernel(
    const float* __restrict__ z, const float* __restrict__ emb,
    const float* __restrict__ enorm, int* __restrict__ idx_out,
    float* __restrict__ idx_out_f, float* __restrict__ counts)
{
    __shared__ float smem[4096];
    float* As = smem;
    float* Bs = smem + 1024;
    const int tid = threadIdx.x;
    const int tx = tid & 15, ty = tid >> 4;
    const int p0 = blockIdx.x * 128;
    const int b = p0 >> 12, hw0 = p0 & 4095;
    const float* zb = z + (size_t)b * (DD * HWSZ) + hw0;
    const int arow = (tid & 31) * 4, akd = tid >> 5;
    const int bcode = tid >> 1, bj = (tid & 1) * 4;
    float best[8]; int bidx[8];
    #pragma unroll
    for (int i = 0; i < 8; i++) { best[i] = 3.4e38f; bidx[i] = 0; }
    #pragma unroll 1
    for (int cc = 0; cc < 8; ++cc) {
        const int c0 = cc * 128;
        float acc[8][8];
        #pragma unroll
        for (int i = 0; i < 8; i++)
            #pragma unroll
            for (int j = 0; j < 8; j++) acc[i][j] = 0.0f;
        #pragma unroll 1
        for (int dk = 0; dk < 32; ++dk) {
            const int kk0 = dk * 8;
            const float4 av = *(const float4*)(zb + (kk0 + akd) * HWSZ + arow);
            const float4 bv = *(const float4*)(emb + (c0 + bcode) * DD + kk0 + bj);
            __syncthreads();
            *(float4*)(As + akd * 128 + arow) = av;
            Bs[(bj + 0) * 128 + bcode] = bv.x;
            Bs[(bj + 1) * 128 + bcode] = bv.y;
            Bs[(bj + 2) * 128 + bcode] = bv.z;
            Bs[(bj + 3) * 128 + bcode] = bv.w;
            __syncthreads();
            #pragma unroll
            for (int kk = 0; kk < 8; ++kk) {
                const float4 a0 = *(const float4*)(As + kk * 128 + ty * 8);
                const float4 a1 = *(const float4*)(As + kk * 128 + ty * 8 + 4);
                const float4 b0 = *(const float4*)(Bs + kk * 128 + tx * 8);
                const float4 b1 = *(const float4*)(Bs + kk * 128 + tx * 8 + 4);
                const float a[8] = {a0.x,a0.y,a0.z,a0.w,a1.x,a1.y,a1.z,a1.w};
                const float bb[8] = {b0.x,b0.y,b0.z,b0.w,b1.x,b1.y,b1.z,b1.w};
                #pragma unroll
                for (int i = 0; i < 8; i++)
                    #pragma unroll
                    for (int j = 0; j < 8; j++)
                        acc[i][j] = fmaf(a[i], bb[j], acc[i][j]);
            }
        }
        const float4 en0 = *(const float4*)(enorm + c0 + tx * 8);
        const float4 en1 = *(const float4*)(enorm + c0 + tx * 8 + 4);
        const float en[8] = {en0.x,en0.y,en0.z,en0.w,en1.x,en1.y,en1.z,en1.w};
        #pragma unroll
        for (int j = 0; j < 8; j++) {
            const int c = c0 + tx * 8 + j;
            #pragma unroll
            for (int i = 0; i < 8; i++) {
                const float dist = fmaf(-2.0f, acc[i][j], en[j]);
                if (dist < best[i]) { best[i] = dist; bidx[i] = c; }
            }
        }
    }
    __syncthreads();
    float* rmin = smem;
    int* ridx = (int*)(smem + 2048);
    #pragma unroll
    for (int i = 0; i < 8; i++) {
        const int r = ty * 8 + i;
        rmin[r * 16 + tx] = best[i];
        ridx[r * 16 + tx] = bidx[i];
    }
    __syncthreads();
    if (tid < 128) {
        const int r = tid;
        float m = rmin[r * 16]; int mi = ridx[r * 16];
        #pragma unroll
        for (int tt = 1; tt < 16; tt++) {
            const float v = rmin[r * 16 + tt];
            const int vi = ridx[r * 16 + tt];
            if (v < m || (v == m && vi < mi)) { m = v; mi = vi; }
        }
        const int p = p0 + r;
        idx_out[p] = mi;
        idx_out_f[p] = (float)mi;
        atomicAdd(&counts[mi], 1.0f);
    }
}

extern "C" void kernel_launch(void* const* d_in, const int* in_sizes, int n_in,
                              void* d_out, int out_size, void* d_ws, size_t ws_size,
                              hipStream_t stream) {
    const float* z       = (const float*)d_in[0];
    const float* emb     = (const float*)d_in[1];
    const float* ema_cs  = (const float*)d_in[2];
    const float* ema_emb = (const float*)d_in[3];
    float* out = (float*)d_out;
    float* ws  = (float*)d_ws;

    int*   ws_idx    = (int*)(ws + WS_IDX);
    float* ws_counts = ws + WS_COUNTS;
    int*   ws_rcnt   = (int*)(ws + WS_RCNT);
    float* ws_lossp  = ws + WS_LOSSP;
    float* ws_enorm  = ws + WS_ENORM;
    int*   ws_rlist  = (int*)(ws + WS_RLIST);
    unsigned short* ws_eaug = (unsigned short*)(ws + WS_EAUG);
    unsigned short* ws_zaug = (unsigned short*)(ws + WS_ZAUG);

    // zero counts + rescue counter
    hipMemsetAsync(ws_counts, 0, 1025 * sizeof(float), stream);
    hipLaunchKernelGGL(enorm_kernel, dim3(KC), dim3(256), 0, stream, emb, ws_enorm);

    if (ws_size >= (size_t)WS_NEED_FLOATS * sizeof(float)) {
        hipLaunchKernelGGL(convert_z_kernel, dim3(8192), dim3(256), 0, stream, z, ws_zaug);
        hipLaunchKernelGGL(convert_emb_kernel, dim3(96), dim3(256), 0, stream, emb, ws_eaug);
        hipLaunchKernelGGL(gemm_argmin_kernel, dim3(1024), dim3(256), 0, stream,
                           ws_zaug, ws_eaug, ws_enorm, ws_idx, out + OUT_IDX,
                           ws_counts, ws_rcnt, ws_rlist);
        hipLaunchKernelGGL(rescue_kernel, dim3(128), dim3(256), 0, stream,
                           z, emb, ws_enorm, ws_rcnt, ws_rlist,
                           ws_idx, out + OUT_IDX, ws_counts);
    } else {
        hipLaunchKernelGGL(dist_argmin_kernel, dim3(NP / 128), dim3(256), 0, stream,
                           z, emb, ws_enorm, ws_idx, out + OUT_IDX, ws_counts);
    }

    hipLaunchKernelGGL(dwq_kernel, dim3(DD), dim3(512), 0, stream,
                       z, emb, ws_idx, ema_emb, out, out + OUT_EMA, ws_lossp);
    hipLaunchKernelGGL(finalize_kernel, dim3(4), dim3(256), 0, stream,
                       ema_cs, ws_counts, ws_lossp, out);
}

// Round 4
// 960.066 us; speedup vs baseline: 5.4902x; 1.2608x over previous
//
#include <hip/hip_runtime.h>

// Problem constants
#define KC 1024          // num codes
#define DD 256           // embedding dim
#define NP 131072        // B*H*W points
#define HWSZ 4096        // H*W
#define TOTZ 33554432    // B*D*H*W

// d_out float offsets (tuple concat: quantized, loss, indices, cluster_size, ema_emb)
#define OUT_Q    0
#define OUT_LOSS 33554432
#define OUT_IDX  33554433
#define OUT_CS   33685505
#define OUT_EMA  33686529

// workspace float offsets
#define WS_IDX    0         // int[131072]
#define WS_COUNTS 131072    // float[1024]
#define WS_RCNT   132096    // int[1]  (memset together with counts: 1025 floats)
#define WS_LOSSP  132352    // float[256]
#define WS_ENORM  132608    // float[1024]
#define WS_RLIST  133632    // int[131072]
#define WS_EAUG   264704    // ushort[786432] = 393216 floats (8 cc x 12 ks x 16KB)
#define WS_ZAUG   657920    // ushort[67108864] = 33554432 floats (1024 pt x 8 ksA x 16KB)
#define WS_NEED_FLOATS (WS_ZAUG + 33554432)

#define MARGIN 0.0625f
#define RTILE 16

typedef __attribute__((ext_vector_type(8))) short bf16x8;
typedef __attribute__((ext_vector_type(4))) float f32x4;

__device__ inline unsigned short f2bf_rne(float x) {
    unsigned u = __float_as_uint(x);
    unsigned r = u + 0x7FFFu + ((u >> 16) & 1u);
    return (unsigned short)(r >> 16);
}
__device__ inline float bf2f(unsigned short h) {
    return __uint_as_float(((unsigned)h) << 16);
}
__device__ inline void gl_lds16(const void* g, void* l) {
    __builtin_amdgcn_global_load_lds(
        (const __attribute__((address_space(1))) unsigned int*)g,
        (__attribute__((address_space(3))) unsigned int*)l, 16, 0, 0);
}
// monotone float->uint, packed with code index: min key = min dist, tie -> min idx
__device__ inline unsigned long long packkey(float d, int c) {
    unsigned u = __float_as_uint(d);
    u = (u & 0x80000000u) ? ~u : (u | 0x80000000u);
    return (((unsigned long long)u) << 32) | (unsigned)c;
}

__global__ __launch_bounds__(256) void enorm_kernel(const float* __restrict__ emb,
                                                    float* __restrict__ enorm) {
    const int k = blockIdx.x;
    float v = emb[k * DD + threadIdx.x];
    v *= v;
    #pragma unroll
    for (int off = 32; off > 0; off >>= 1) v += __shfl_down(v, off);
    __shared__ float red[4];
    if ((threadIdx.x & 63) == 0) red[threadIdx.x >> 6] = v;
    __syncthreads();
    if (threadIdx.x == 0) enorm[k] = (red[0] + red[1]) + (red[2] + red[3]);
}

// z_aug: [pt(1024)][ksA(8)][kc(2)][mt(8)][lane(64)][8 bf16]
// ksA 0..3 = hi(k = ksA*64 + ...), ksA 4..7 = mid.  (GEMM maps ks 8..11 -> phys 0..3)
__global__ __launch_bounds__(256) void convert_z_kernel(
    const float* __restrict__ z, unsigned short* __restrict__ zaug)
{
    const int blk = blockIdx.x;            // pt*8 + ksA
    const int pt = blk >> 3, ksA = blk & 7;
    const int mode = ksA >> 2;             // 0 hi, 1 mid
    const int kbase0 = (ksA & 3) * 64;
    unsigned short* outp = zaug + (size_t)blk * 8192;
    #pragma unroll
    for (int i = 0; i < 4; ++i) {
        const int f = i * 256 + threadIdx.x;   // fragment index [0,1024)
        const int kc = f >> 9, mt = (f >> 6) & 7, lane = f & 63;
        const int q = lane >> 4, col = lane & 15;
        const int p = pt * 128 + mt * 16 + col;
        const int b = p >> 12, hw = p & 4095;
        const int k0 = kbase0 + kc * 32 + q * 8;
        const float* src = z + (size_t)b * 1048576 + (size_t)k0 * 4096 + hw;
        unsigned short v[8];
        #pragma unroll
        for (int j = 0; j < 8; ++j) {
            const float x = src[j * 4096];
            const unsigned short h = f2bf_rne(x);
            v[j] = mode ? f2bf_rne(x - bf2f(h)) : h;
        }
        *(uint4*)(outp + (size_t)f * 8) = *(uint4*)v;
    }
}

// emb_aug: [cc(8)][ks(12)][kc(2)][nt(8)][lane(64)][8 bf16]; ks 0..7 = hi, 8..11 = mid
__global__ __launch_bounds__(256) void convert_emb_kernel(
    const float* __restrict__ emb, unsigned short* __restrict__ eaug)
{
    const int blk = blockIdx.x;            // cc*12 + ks
    const int cc = blk / 12, ks = blk % 12;
    const int mode = (ks >= 8);
    unsigned short* outp = eaug + (size_t)blk * 8192;
    #pragma unroll
    for (int i = 0; i < 4; ++i) {
        const int f = i * 256 + threadIdx.x;
        const int kc = f >> 9, nt = (f >> 6) & 7, lane = f & 63;
        const int q = lane >> 4, col = lane & 15;
        const int n = cc * 128 + nt * 16 + col;
        const int k0 = ((ks * 64) & 255) + kc * 32 + q * 8;
        const float* src = emb + (size_t)n * 256 + k0;
        unsigned short v[8];
        #pragma unroll
        for (int j = 0; j < 8; ++j) {
            const float x = src[j];
            const unsigned short h = f2bf_rne(x);
            v[j] = mode ? f2bf_rne(x - bf2f(h)) : h;
        }
        *(uint4*)(outp + (size_t)f * 8) = *(uint4*)v;
    }
}

// MFMA GEMM + fused argmin. Block: 128 points x (8 cc chunks of 128 codes).
// 4 waves, each 64x64 quadrant (mh = w&1, nh = w>>1).
__global__ __launch_bounds__(256) void gemm_argmin_kernel(
    const unsigned short* __restrict__ zaug, const unsigned short* __restrict__ eaug,
    const float* __restrict__ enorm, int* __restrict__ idx_out,
    float* __restrict__ idx_out_f, float* __restrict__ counts,
    int* __restrict__ rcnt, int* __restrict__ rlist)
{
    __shared__ float smem[12288];                      // 48 KB
    unsigned short* aS = (unsigned short*)smem;        // 8192 hw (16 KB)
    unsigned short* bS = (unsigned short*)(smem + 4096);
    const int t = threadIdx.x, w = t >> 6, lane = t & 63;
    const int mh = w & 1, nh = w >> 1;
    const int pt = blockIdx.x;

    float rb[16], rs[16]; int ri[16];
    #pragma unroll
    for (int s = 0; s < 16; ++s) { rb[s] = 3.4e38f; rs[s] = 3.4e38f; ri[s] = 0; }

    #pragma unroll 1
    for (int cc = 0; cc < 8; ++cc) {
        f32x4 acc[4][4];
        #pragma unroll
        for (int mi = 0; mi < 4; ++mi)
            #pragma unroll
            for (int ni = 0; ni < 4; ++ni) acc[mi][ni] = (f32x4){0.f, 0.f, 0.f, 0.f};

        float en[4];
        #pragma unroll
        for (int ni = 0; ni < 4; ++ni)
            en[ni] = enorm[cc * 128 + nh * 64 + ni * 16 + (lane & 15)];

        #pragma unroll 1
        for (int ks = 0; ks < 12; ++ks) {
            const int ksA = (ks < 8) ? ks : (ks - 8);
            const unsigned short* ga = zaug + ((size_t)(pt * 8 + ksA)) * 8192;
            const unsigned short* gb = eaug + ((size_t)(cc * 12 + ks)) * 8192;
            #pragma unroll
            for (int i = 0; i < 4; ++i) {
                const int off = i * 2048 + w * 512 + lane * 8;   // halfwords
                gl_lds16(ga + off, aS + off);
                gl_lds16(gb + off, bS + off);
            }
            __syncthreads();
            #pragma unroll
            for (int kc = 0; kc < 2; ++kc) {
                bf16x8 af[4], bf[4];
                #pragma unroll
                for (int mi = 0; mi < 4; ++mi)
                    af[mi] = *(const bf16x8*)(aS + kc * 4096 + (mh * 4 + mi) * 512 + lane * 8);
                #pragma unroll
                for (int ni = 0; ni < 4; ++ni)
                    bf[ni] = *(const bf16x8*)(bS + kc * 4096 + (nh * 4 + ni) * 512 + lane * 8);
                #pragma unroll
                for (int mi = 0; mi < 4; ++mi)
                    #pragma unroll
                    for (int ni = 0; ni < 4; ++ni)
                        acc[mi][ni] = __builtin_amdgcn_mfma_f32_16x16x32_bf16(
                            af[mi], bf[ni], acc[mi][ni], 0, 0, 0);
            }
            __syncthreads();
        }
        // epilogue: dist = enorm - 2*dot; per-slot (min, 2nd, idx) over 4 nt, merge
        #pragma unroll
        for (int mi = 0; mi < 4; ++mi) {
            #pragma unroll
            for (int r = 0; r < 4; ++r) {
                const int s = mi * 4 + r;
                float v0 = fmaf(-2.f, acc[mi][0][r], en[0]);
                float v1 = fmaf(-2.f, acc[mi][1][r], en[1]);
                float v2 = fmaf(-2.f, acc[mi][2][r], en[2]);
                float v3 = fmaf(-2.f, acc[mi][3][r], en[3]);
                const int nb = cc * 128 + nh * 64 + (lane & 15);
                float b01 = fminf(v0, v1), x01 = fmaxf(v0, v1);
                int   i01 = (v1 < v0) ? nb + 16 : nb;
                float b23 = fminf(v2, v3), x23 = fmaxf(v2, v3);
                int   i23 = (v3 < v2) ? nb + 48 : nb + 32;
                float b = fminf(b01, b23);
                int   ib = (b23 < b01) ? i23 : i01;
                float s2 = fminf(fmaxf(b01, b23), fminf(x01, x23));
                if (b < rb[s]) { rs[s] = fminf(rb[s], s2); rb[s] = b; ri[s] = ib; }
                else           { rs[s] = fminf(rs[s], b); }
            }
        }
    }

    // dump per-lane running state to LDS, then threads 0..127 finalize one point each
    #pragma unroll
    for (int s = 0; s < 16; ++s) {
        smem[w * 1024 + s * 64 + lane] = rb[s];
        smem[4096 + w * 1024 + s * 64 + lane] = rs[s];
        ((int*)smem)[8192 + w * 1024 + s * 64 + lane] = ri[s];
    }
    __syncthreads();
    if (t < 128) {
        const int mi = (t >> 4) & 3, q = (t >> 2) & 3, r = t & 3;
        const int s = mi * 4 + r;
        float B = 3.4e38f, S = 3.4e38f; int I = 0;
        #pragma unroll
        for (int h = 0; h < 2; ++h) {
            const int wv = (t >> 6) + h * 2;
            const int base = wv * 1024 + s * 64 + q * 16;
            #pragma unroll
            for (int ln = 0; ln < 16; ++ln) {
                const float b = smem[base + ln];
                const float s2 = smem[4096 + base + ln];
                const int   i = ((int*)smem)[8192 + base + ln];
                if (b < B) { S = fminf(B, s2); B = b; I = i; }
                else       { S = fminf(S, b); }
            }
        }
        const int p = pt * 128 + t;
        idx_out[p] = I;
        idx_out_f[p] = (float)I;
        atomicAdd(&counts[I], 1.0f);
        if (S - B < MARGIN) {
            const int pos = atomicAdd(rcnt, 1);
            rlist[pos] = p;
        }
    }
}

// Batched exact fp32 re-argmin: 16 rescue points per tile staged in LDS; each
// thread owns 4 codes and streams emb ONCE per tile (reused across 16 points;
// LDS reads are same-address broadcasts). Cross-thread argmin via packed u64
// atomicMin (min dist, tie -> min idx). Dot order identical to R3 rescue.
__global__ __launch_bounds__(256) void rescue_kernel(
    const float* __restrict__ z, const float* __restrict__ emb,
    const float* __restrict__ enorm, const int* __restrict__ rcnt,
    const int* __restrict__ rlist, int* __restrict__ idx_out,
    float* __restrict__ idx_out_f, float* __restrict__ counts)
{
    __shared__ float zl[RTILE][DD];
    __shared__ unsigned long long lkey[RTILE];
    const int n = *rcnt;
    if (n <= 0) return;
    const int ntiles = (n + RTILE - 1) / RTILE;
    const int t = threadIdx.x;
    const int slot = t & 15, drow = t >> 4;    // thread loads 16 dims for one slot
    #pragma unroll 1
    for (int tile = blockIdx.x; tile < ntiles; tile += gridDim.x) {
        const int base = tile * RTILE;
        {
            const int ridx = min(base + slot, n - 1);   // clamp: dup compute, guarded update
            const int p = rlist[ridx];
            const int b = p >> 12, hw = p & 4095;
            const float* zp = z + (size_t)b * 1048576 + hw;
            #pragma unroll
            for (int j = 0; j < 16; ++j)
                zl[slot][drow * 16 + j] = zp[(size_t)(drow * 16 + j) * 4096];
        }
        if (t < RTILE) lkey[t] = ~0ull;
        __syncthreads();
        unsigned long long bkey[RTILE];
        #pragma unroll
        for (int p = 0; p < RTILE; ++p) bkey[p] = ~0ull;
        #pragma unroll 1
        for (int ci = 0; ci < 4; ++ci) {
            const int c = ci * 256 + t;
            const float* e = emb + (size_t)c * 256;
            float dot[RTILE];
            #pragma unroll
            for (int p = 0; p < RTILE; ++p) dot[p] = 0.f;
            #pragma unroll 1
            for (int d4 = 0; d4 < DD; d4 += 4) {
                const float4 ev = *(const float4*)(e + d4);
                #pragma unroll
                for (int p = 0; p < RTILE; ++p) {
                    const float4 zv = *(const float4*)(&zl[p][d4]);
                    dot[p] = fmaf(zv.x, ev.x, dot[p]);
                    dot[p] = fmaf(zv.y, ev.y, dot[p]);
                    dot[p] = fmaf(zv.z, ev.z, dot[p]);
                    dot[p] = fmaf(zv.w, ev.w, dot[p]);
                }
            }
            const float en = enorm[c];
            #pragma unroll
            for (int p = 0; p < RTILE; ++p) {
                const unsigned long long k = packkey(fmaf(-2.f, dot[p], en), c);
                bkey[p] = (k < bkey[p]) ? k : bkey[p];
            }
        }
        #pragma unroll
        for (int p = 0; p < RTILE; ++p) atomicMin(&lkey[p], bkey[p]);
        __syncthreads();
        if (t < RTILE && base + t < n) {
            const int p = rlist[base + t];
            const int fc = (int)(lkey[t] & 0xFFFFFFFFull);
            const int old = idx_out[p];
            if (fc != old) {
                atomicAdd(&counts[old], -1.0f);
                atomicAdd(&counts[fc], 1.0f);
                idx_out[p] = fc;
                idx_out_f[p] = (float)fc;
            }
        }
        __syncthreads();
    }
}

// Fused quantize + dw-segment-sum + loss. Block = one dim d (256 blocks x 512 thr).
__global__ __launch_bounds__(512) void dwq_kernel(
    const float* __restrict__ z, const float* __restrict__ emb,
    const int* __restrict__ idx, const float* __restrict__ ema_emb,
    float* __restrict__ out_q, float* __restrict__ out_ema,
    float* __restrict__ lossp)
{
    __shared__ float kdw[KC];
    __shared__ float ecol[KC];
    __shared__ float red[8];
    const int d = blockIdx.x;
    const int t = threadIdx.x;
    #pragma unroll
    for (int k = t; k < KC; k += 512) { kdw[k] = 0.f; ecol[k] = emb[(size_t)k * 256 + d]; }
    __syncthreads();
    float ls = 0.f;
    #pragma unroll 1
    for (int it = 0; it < 64; ++it) {
        const int e = it * 512 + t;            // float4-unit over (b, hw)
        const int b = e >> 10, hwi = (e & 1023) << 2;
        const size_t zoff = (size_t)b * 1048576 + (size_t)d * 4096 + hwi;
        const float4 zv = *(const float4*)(z + zoff);
        const int4 iv = *(const int4*)(idx + b * 4096 + hwi);
        const float q0 = ecol[iv.x], q1 = ecol[iv.y], q2 = ecol[iv.z], q3 = ecol[iv.w];
        float4 qv; qv.x = q0; qv.y = q1; qv.z = q2; qv.w = q3;
        *(float4*)(out_q + zoff) = qv;
        atomicAdd(&kdw[iv.x], zv.x);
        atomicAdd(&kdw[iv.y], zv.y);
        atomicAdd(&kdw[iv.z], zv.z);
        atomicAdd(&kdw[iv.w], zv.w);
        const float d0 = zv.x - q0, d1 = zv.y - q1, d2 = zv.z - q2, d3 = zv.w - q3;
        ls += (d0 * d0 + d1 * d1) + (d2 * d2 + d3 * d3);
    }
    __syncthreads();
    #pragma unroll
    for (int k = t; k < KC; k += 512)
        out_ema[(size_t)k * 256 + d] = 0.99f * ema_emb[(size_t)k * 256 + d] + 0.01f * kdw[k];
    #pragma unroll
    for (int off = 32; off > 0; off >>= 1) ls += __shfl_down(ls, off);
    if ((t & 63) == 0) red[t >> 6] = ls;
    __syncthreads();
    if (t == 0) {
        float s = 0.f;
        #pragma unroll
        for (int i = 0; i < 8; ++i) s += red[i];
        lossp[blockIdx.x] = s;
    }
}

__global__ __launch_bounds__(256) void finalize_kernel(
    const float* __restrict__ ema_cs, const float* __restrict__ counts,
    const float* __restrict__ lossp, float* __restrict__ out)
{
    const int i = blockIdx.x * 256 + threadIdx.x;   // 4 blocks
    out[OUT_CS + i] = 0.99f * ema_cs[i] + 0.01f * counts[i];
    if (blockIdx.x == 0) {
        float s = lossp[threadIdx.x];
        #pragma unroll
        for (int off = 32; off > 0; off >>= 1) s += __shfl_down(s, off);
        __shared__ float red[4];
        if ((threadIdx.x & 63) == 0) red[threadIdx.x >> 6] = s;
        __syncthreads();
        if (threadIdx.x == 0)
            out[OUT_LOSS] = 0.25f * ((red[0] + red[1]) + (red[2] + red[3])) / 33554432.0f;
    }
}

// ---------- fallback fp32 GEMM (R2 path, used if ws too small) ----------
__global__ __launch_bounds__(256) void dist_argmin_kernel(
    const float* __restrict__ z, const float* __restrict__ emb,
    const float* __restrict__ enorm, int* __restrict__ idx_out,
    float* __restrict__ idx_out_f, float* __restrict__ counts)
{
    __shared__ float smem[4096];
    float* As = smem;
    float* Bs = smem + 1024;
    const int tid = threadIdx.x;
    const int tx = tid & 15, ty = tid >> 4;
    const int p0 = blockIdx.x * 128;
    const int b = p0 >> 12, hw0 = p0 & 4095;
    const float* zb = z + (size_t)b * (DD * HWSZ) + hw0;
    const int arow = (tid & 31) * 4, akd = tid >> 5;
    const int bcode = tid >> 1, bj = (tid & 1) * 4;
    float best[8]; int bidx[8];
    #pragma unroll
    for (int i = 0; i < 8; i++) { best[i] = 3.4e38f; bidx[i] = 0; }
    #pragma unroll 1
    for (int cc = 0; cc < 8; ++cc) {
        const int c0 = cc * 128;
        float acc[8][8];
        #pragma unroll
        for (int i = 0; i < 8; i++)
            #pragma unroll
            for (int j = 0; j < 8; j++) acc[i][j] = 0.0f;
        #pragma unroll 1
        for (int dk = 0; dk < 32; ++dk) {
            const int kk0 = dk * 8;
            const float4 av = *(const float4*)(zb + (kk0 + akd) * HWSZ + arow);
            const float4 bv = *(const float4*)(emb + (c0 + bcode) * DD + kk0 + bj);
            __syncthreads();
            *(float4*)(As + akd * 128 + arow) = av;
            Bs[(bj + 0) * 128 + bcode] = bv.x;
            Bs[(bj + 1) * 128 + bcode] = bv.y;
            Bs[(bj + 2) * 128 + bcode] = bv.z;
            Bs[(bj + 3) * 128 + bcode] = bv.w;
            __syncthreads();
            #pragma unroll
            for (int kk = 0; kk < 8; ++kk) {
                const float4 a0 = *(const float4*)(As + kk * 128 + ty * 8);
                const float4 a1 = *(const float4*)(As + kk * 128 + ty * 8 + 4);
                const float4 b0 = *(const float4*)(Bs + kk * 128 + tx * 8);
                const float4 b1 = *(const float4*)(Bs + kk * 128 + tx * 8 + 4);
                const float a[8] = {a0.x,a0.y,a0.z,a0.w,a1.x,a1.y,a1.z,a1.w};
                const float bb[8] = {b0.x,b0.y,b0.z,b0.w,b1.x,b1.y,b1.z,b1.w};
                #pragma unroll
                for (int i = 0; i < 8; i++)
                    #pragma unroll
                    for (int j = 0; j < 8; j++)
                        acc[i][j] = fmaf(a[i], bb[j], acc[i][j]);
            }
        }
        const float4 en0 = *(const float4*)(enorm + c0 + tx * 8);
        const float4 en1 = *(const float4*)(enorm + c0 + tx * 8 + 4);
        const float en[8] = {en0.x,en0.y,en0.z,en0.w,en1.x,en1.y,en1.z,en1.w};
        #pragma unroll
        for (int j = 0; j < 8; j++) {
            const int c = c0 + tx * 8 + j;
            #pragma unroll
            for (int i = 0; i < 8; i++) {
                const float dist = fmaf(-2.0f, acc[i][j], en[j]);
                if (dist < best[i]) { best[i] = dist; bidx[i] = c; }
            }
        }
    }
    __syncthreads();
    float* rmin = smem;
    int* ridx = (int*)(smem + 2048);
    #pragma unroll
    for (int i = 0; i < 8; i++) {
        const int r = ty * 8 + i;
        rmin[r * 16 + tx] = best[i];
        ridx[r * 16 + tx] = bidx[i];
    }
    __syncthreads();
    if (tid < 128) {
        const int r = tid;
        float m = rmin[r * 16]; int mi = ridx[r * 16];
        #pragma unroll
        for (int tt = 1; tt < 16; tt++) {
            const float v = rmin[r * 16 + tt];
            const int vi = ridx[r * 16 + tt];
            if (v < m || (v == m && vi < mi)) { m = v; mi = vi; }
        }
        const int p = p0 + r;
        idx_out[p] = mi;
        idx_out_f[p] = (float)mi;
        atomicAdd(&counts[mi], 1.0f);
    }
}

extern "C" void kernel_launch(void* const* d_in, const int* in_sizes, int n_in,
                              void* d_out, int out_size, void* d_ws, size_t ws_size,
                              hipStream_t stream) {
    const float* z       = (const float*)d_in[0];
    const float* emb     = (const float*)d_in[1];
    const float* ema_cs  = (const float*)d_in[2];
    const float* ema_emb = (const float*)d_in[3];
    float* out = (float*)d_out;
    float* ws  = (float*)d_ws;

    int*   ws_idx    = (int*)(ws + WS_IDX);
    float* ws_counts = ws + WS_COUNTS;
    int*   ws_rcnt   = (int*)(ws + WS_RCNT);
    float* ws_lossp  = ws + WS_LOSSP;
    float* ws_enorm  = ws + WS_ENORM;
    int*   ws_rlist  = (int*)(ws + WS_RLIST);
    unsigned short* ws_eaug = (unsigned short*)(ws + WS_EAUG);
    unsigned short* ws_zaug = (unsigned short*)(ws + WS_ZAUG);

    // zero counts + rescue counter
    hipMemsetAsync(ws_counts, 0, 1025 * sizeof(float), stream);
    hipLaunchKernelGGL(enorm_kernel, dim3(KC), dim3(256), 0, stream, emb, ws_enorm);

    if (ws_size >= (size_t)WS_NEED_FLOATS * sizeof(float)) {
        hipLaunchKernelGGL(convert_z_kernel, dim3(8192), dim3(256), 0, stream, z, ws_zaug);
        hipLaunchKernelGGL(convert_emb_kernel, dim3(96), dim3(256), 0, stream, emb, ws_eaug);
        hipLaunchKernelGGL(gemm_argmin_kernel, dim3(1024), dim3(256), 0, stream,
                           ws_zaug, ws_eaug, ws_enorm, ws_idx, out + OUT_IDX,
                           ws_counts, ws_rcnt, ws_rlist);
        hipLaunchKernelGGL(rescue_kernel, dim3(256), dim3(256), 0, stream,
                           z, emb, ws_enorm, ws_rcnt, ws_rlist,
                           ws_idx, out + OUT_IDX, ws_counts);
    } else {
        hipLaunchKernelGGL(dist_argmin_kernel, dim3(NP / 128), dim3(256), 0, stream,
                           z, emb, ws_enorm, ws_idx, out + OUT_IDX, ws_counts);
    }

    hipLaunchKernelGGL(dwq_kernel, dim3(DD), dim3(512), 0, stream,
                       z, emb, ws_idx, ema_emb, out, out + OUT_EMA, ws_lossp);
    hipLaunchKernelGGL(finalize_kernel, dim3(4), dim3(256), 0, stream,
                       ema_cs, ws_counts, ws_lossp, out);
}

// Round 5
// 863.325 us; speedup vs baseline: 6.1054x; 1.1121x over previous
//
#include <hip/hip_runtime.h>

// Problem constants
#define KC 1024          // num codes
#define DD 256           // embedding dim
#define NP 131072        // B*H*W points
#define HWSZ 4096        // H*W
#define TOTZ 33554432    // B*D*H*W

// d_out float offsets (tuple concat: quantized, loss, indices, cluster_size, ema_emb)
#define OUT_Q    0
#define OUT_LOSS 33554432
#define OUT_IDX  33554433
#define OUT_CS   33685505
#define OUT_EMA  33686529

// workspace float offsets
#define WS_IDX    0         // int[131072]
#define WS_COUNTS 131072    // float[1024]
#define WS_RCNT   132096    // int[1]  (memset together with counts: 1025 floats)
#define WS_LOSSP  132352    // float[256]
#define WS_ENORM  132608    // float[1024]
#define WS_RLIST  133632    // int[131072]
#define WS_EAUG   264704    // ushort[786432] = 393216 floats (8 cc x 12 ks x 16KB)
#define WS_ZAUG   657920    // ushort[67108864] = 33554432 floats (1024 pt x 8 ksA x 16KB)
#define WS_NEED_FLOATS (WS_ZAUG + 33554432)

#define MARGIN 0.0625f
#define RTILE 16

typedef __attribute__((ext_vector_type(8))) short bf16x8;
typedef __attribute__((ext_vector_type(4))) float f32x4;

__device__ inline unsigned short f2bf_rne(float x) {
    unsigned u = __float_as_uint(x);
    unsigned r = u + 0x7FFFu + ((u >> 16) & 1u);
    return (unsigned short)(r >> 16);
}
__device__ inline float bf2f(unsigned short h) {
    return __uint_as_float(((unsigned)h) << 16);
}
__device__ inline void gl_lds16(const void* g, void* l) {
    __builtin_amdgcn_global_load_lds(
        (const __attribute__((address_space(1))) unsigned int*)g,
        (__attribute__((address_space(3))) unsigned int*)l, 16, 0, 0);
}
// monotone float->uint, packed with code index: min key = min dist, tie -> min idx
__device__ inline unsigned long long packkey(float d, int c) {
    unsigned u = __float_as_uint(d);
    u = (u & 0x80000000u) ? ~u : (u | 0x80000000u);
    return (((unsigned long long)u) << 32) | (unsigned)c;
}

__global__ __launch_bounds__(256) void enorm_kernel(const float* __restrict__ emb,
                                                    float* __restrict__ enorm) {
    const int k = blockIdx.x;
    float v = emb[k * DD + threadIdx.x];
    v *= v;
    #pragma unroll
    for (int off = 32; off > 0; off >>= 1) v += __shfl_down(v, off);
    __shared__ float red[4];
    if ((threadIdx.x & 63) == 0) red[threadIdx.x >> 6] = v;
    __syncthreads();
    if (threadIdx.x == 0) enorm[k] = (red[0] + red[1]) + (red[2] + red[3]);
}

// z_aug: [pt(1024)][ksA(8)][kc(2)][mt(8)][lane(64)][8 bf16]
// ksA 0..3 = hi, 4..7 = mid. Fused: one block computes hi AND mid (z read once).
__global__ __launch_bounds__(256) void convert_z_kernel(
    const float* __restrict__ z, unsigned short* __restrict__ zaug)
{
    const int blk = blockIdx.x;            // pt*4 + kslot
    const int pt = blk >> 2, kslot = blk & 3;
    const int kbase0 = kslot * 64;
    unsigned short* outH = zaug + (size_t)(pt * 8 + kslot) * 8192;
    unsigned short* outM = zaug + (size_t)(pt * 8 + 4 + kslot) * 8192;
    #pragma unroll
    for (int i = 0; i < 4; ++i) {
        const int f = i * 256 + threadIdx.x;   // fragment index [0,1024)
        const int kc = f >> 9, mt = (f >> 6) & 7, lane = f & 63;
        const int q = lane >> 4, col = lane & 15;
        const int p = pt * 128 + mt * 16 + col;
        const int b = p >> 12, hw = p & 4095;
        const int k0 = kbase0 + kc * 32 + q * 8;
        const float* src = z + (size_t)b * 1048576 + (size_t)k0 * 4096 + hw;
        unsigned short vh[8], vm[8];
        #pragma unroll
        for (int j = 0; j < 8; ++j) {
            const float x = src[j * 4096];
            const unsigned short h = f2bf_rne(x);
            vh[j] = h;
            vm[j] = f2bf_rne(x - bf2f(h));
        }
        *(uint4*)(outH + (size_t)f * 8) = *(uint4*)vh;
        *(uint4*)(outM + (size_t)f * 8) = *(uint4*)vm;
    }
}

// emb_aug: [cc(8)][ks(12)][kc(2)][nt(8)][lane(64)][8 bf16]; ks 0..7 = hi, 8..11 = mid
__global__ __launch_bounds__(256) void convert_emb_kernel(
    const float* __restrict__ emb, unsigned short* __restrict__ eaug)
{
    const int blk = blockIdx.x;            // cc*12 + ks
    const int cc = blk / 12, ks = blk % 12;
    const int mode = (ks >= 8);
    unsigned short* outp = eaug + (size_t)blk * 8192;
    #pragma unroll
    for (int i = 0; i < 4; ++i) {
        const int f = i * 256 + threadIdx.x;
        const int kc = f >> 9, nt = (f >> 6) & 7, lane = f & 63;
        const int q = lane >> 4, col = lane & 15;
        const int n = cc * 128 + nt * 16 + col;
        const int k0 = ((ks * 64) & 255) + kc * 32 + q * 8;
        const float* src = emb + (size_t)n * 256 + k0;
        unsigned short v[8];
        #pragma unroll
        for (int j = 0; j < 8; ++j) {
            const float x = src[j];
            const unsigned short h = f2bf_rne(x);
            v[j] = mode ? f2bf_rne(x - bf2f(h)) : h;
        }
        *(uint4*)(outp + (size_t)f * 8) = *(uint4*)v;
    }
}

// MFMA GEMM + fused argmin. Block: 128 points x 1024 codes, 512 threads = 8 waves.
// cc processed in pairs: waves 0-3 (cho=0) compute cc=2pp, waves 4-7 cc=2pp+1,
// sharing one A stage. Per-wave tile 64x64 (mh=w2&1, nh=w2>>1) -- identical math
// to the 256-thread version.
__global__ __launch_bounds__(512) void gemm_argmin_kernel(
    const unsigned short* __restrict__ zaug, const unsigned short* __restrict__ eaug,
    const float* __restrict__ enorm, int* __restrict__ idx_out,
    float* __restrict__ idx_out_f, float* __restrict__ counts,
    int* __restrict__ rcnt, int* __restrict__ rlist)
{
    __shared__ float smem[12288];                      // 48 KB
    unsigned short* aS   = (unsigned short*)smem;      // 8192 hw (16 KB)
    unsigned short* bAll = aS + 8192;                  // 16384 hw (32 KB): bS0 | bS1
    const int t = threadIdx.x, w = t >> 6, lane = t & 63;
    const int w2 = w & 3, cho = w >> 2;
    const int mh = w2 & 1, nh = w2 >> 1;
    const int pt = blockIdx.x;

    const int aoff = w * 1024 + lane * 8;              // hw; +512 for 2nd inst
    const int boff = w * 2048 + lane * 8;              // hw; +j*512, j=0..3

    float rb[16], rs[16]; int ri[16];
    #pragma unroll
    for (int s = 0; s < 16; ++s) { rb[s] = 3.4e38f; rs[s] = 3.4e38f; ri[s] = 0; }

    #pragma unroll 1
    for (int pp = 0; pp < 4; ++pp) {
        const int cc = pp * 2 + cho;
        f32x4 acc[4][4];
        #pragma unroll
        for (int mi = 0; mi < 4; ++mi)
            #pragma unroll
            for (int ni = 0; ni < 4; ++ni) acc[mi][ni] = (f32x4){0.f, 0.f, 0.f, 0.f};

        float en[4];
        #pragma unroll
        for (int ni = 0; ni < 4; ++ni)
            en[ni] = enorm[cc * 128 + nh * 64 + ni * 16 + (lane & 15)];

        #pragma unroll 1
        for (int ks = 0; ks < 12; ++ks) {
            const int ksA = (ks < 8) ? ks : (ks - 8);
            const unsigned short* ga = zaug + ((size_t)(pt * 8 + ksA)) * 8192;
            // waves 0-3 stage B of cc-even into bAll[0..8191], waves 4-7 stage
            // cc-odd into bAll[8192..16383]
            const unsigned short* gbase = (w < 4)
                ? eaug + ((size_t)((pp * 2 + 0) * 12 + ks)) * 8192
                : eaug + ((size_t)((pp * 2 + 1) * 12 + ks)) * 8192 - 8192;
            __syncthreads();
            gl_lds16(ga + aoff, aS + aoff);
            gl_lds16(ga + aoff + 512, aS + aoff + 512);
            #pragma unroll
            for (int j = 0; j < 4; ++j)
                gl_lds16(gbase + boff + j * 512, bAll + boff + j * 512);
            __syncthreads();
            #pragma unroll
            for (int kc = 0; kc < 2; ++kc) {
                bf16x8 af[4], bf[4];
                #pragma unroll
                for (int mi = 0; mi < 4; ++mi)
                    af[mi] = *(const bf16x8*)(aS + kc * 4096 + (mh * 4 + mi) * 512 + lane * 8);
                #pragma unroll
                for (int ni = 0; ni < 4; ++ni)
                    bf[ni] = *(const bf16x8*)(bAll + cho * 8192 + kc * 4096 + (nh * 4 + ni) * 512 + lane * 8);
                #pragma unroll
                for (int mi = 0; mi < 4; ++mi)
                    #pragma unroll
                    for (int ni = 0; ni < 4; ++ni)
                        acc[mi][ni] = __builtin_amdgcn_mfma_f32_16x16x32_bf16(
                            af[mi], bf[ni], acc[mi][ni], 0, 0, 0);
            }
        }
        // epilogue: dist = enorm - 2*dot; per-slot (min, 2nd, idx) over 4 nt, merge
        #pragma unroll
        for (int mi = 0; mi < 4; ++mi) {
            #pragma unroll
            for (int r = 0; r < 4; ++r) {
                const int s = mi * 4 + r;
                float v0 = fmaf(-2.f, acc[mi][0][r], en[0]);
                float v1 = fmaf(-2.f, acc[mi][1][r], en[1]);
                float v2 = fmaf(-2.f, acc[mi][2][r], en[2]);
                float v3 = fmaf(-2.f, acc[mi][3][r], en[3]);
                const int nb = cc * 128 + nh * 64 + (lane & 15);
                float b01 = fminf(v0, v1), x01 = fmaxf(v0, v1);
                int   i01 = (v1 < v0) ? nb + 16 : nb;
                float b23 = fminf(v2, v3), x23 = fmaxf(v2, v3);
                int   i23 = (v3 < v2) ? nb + 48 : nb + 32;
                float b = fminf(b01, b23);
                int   ib = (b23 < b01) ? i23 : i01;
                float s2 = fminf(fmaxf(b01, b23), fminf(x01, x23));
                if (b < rb[s]) { rs[s] = fminf(rb[s], s2); rb[s] = b; ri[s] = ib; }
                else           { rs[s] = fminf(rs[s], b); }
            }
        }
    }

    // two-phase dump (cho=0 then cho=1; 4 waves x 16 slots x 64 lanes fits 48 KB),
    // threads 0..127 merge one point each across both phases.
    float B = 3.4e38f, S = 3.4e38f; int I = 0;
    const int mi_f = (t >> 4) & 3, q_f = (t >> 2) & 3, r_f = t & 3;
    const int s_f = mi_f * 4 + r_f;
    #pragma unroll 1
    for (int phase = 0; phase < 2; ++phase) {
        __syncthreads();
        if (cho == phase) {
            #pragma unroll
            for (int s = 0; s < 16; ++s) {
                smem[w2 * 1024 + s * 64 + lane] = rb[s];
                smem[4096 + w2 * 1024 + s * 64 + lane] = rs[s];
                ((int*)smem)[8192 + w2 * 1024 + s * 64 + lane] = ri[s];
            }
        }
        __syncthreads();
        if (t < 128) {
            #pragma unroll
            for (int hh = 0; hh < 2; ++hh) {
                const int wv = (t >> 6) + hh * 2;
                const int base = wv * 1024 + s_f * 64 + q_f * 16;
                #pragma unroll
                for (int ln = 0; ln < 16; ++ln) {
                    const float b = smem[base + ln];
                    const float s2 = smem[4096 + base + ln];
                    const int   i = ((int*)smem)[8192 + base + ln];
                    if (b < B) { S = fminf(B, s2); B = b; I = i; }
                    else       { S = fminf(S, b); }
                }
            }
        }
    }
    if (t < 128) {
        const int p = pt * 128 + t;
        idx_out[p] = I;
        idx_out_f[p] = (float)I;
        atomicAdd(&counts[I], 1.0f);
        if (S - B < MARGIN) {
            const int pos = atomicAdd(rcnt, 1);
            rlist[pos] = p;
        }
    }
}

// Batched exact fp32 re-argmin: 16 points staged in LDS, each thread owns 4
// codes (c = ci*256 + t) with dot[16][4] register accumulators -> per d4 only
// 16 LDS reads + 4 e-loads for 256 FMA. Numerics identical to prior version.
__global__ __launch_bounds__(256) void rescue_kernel(
    const float* __restrict__ z, const float* __restrict__ emb,
    const float* __restrict__ enorm, const int* __restrict__ rcnt,
    const int* __restrict__ rlist, int* __restrict__ idx_out,
    float* __restrict__ idx_out_f, float* __restrict__ counts)
{
    __shared__ float zl[RTILE][DD];
    __shared__ unsigned long long lkey[RTILE];
    const int n = *rcnt;
    if (n <= 0) return;
    const int ntiles = (n + RTILE - 1) / RTILE;
    const int t = threadIdx.x;
    const int slot = t & 15, drow = t >> 4;    // thread loads 16 dims for one slot
    #pragma unroll 1
    for (int tile = blockIdx.x; tile < ntiles; tile += gridDim.x) {
        const int base = tile * RTILE;
        {
            const int ridx = min(base + slot, n - 1);   // clamp: dup compute, guarded update
            const int p = rlist[ridx];
            const int b = p >> 12, hw = p & 4095;
            const float* zp = z + (size_t)b * 1048576 + hw;
            #pragma unroll
            for (int j = 0; j < 16; ++j)
                zl[slot][drow * 16 + j] = zp[(size_t)(drow * 16 + j) * 4096];
        }
        if (t < RTILE) lkey[t] = ~0ull;
        __syncthreads();
        float dot[RTILE][4];
        #pragma unroll
        for (int p = 0; p < RTILE; ++p)
            #pragma unroll
            for (int ci = 0; ci < 4; ++ci) dot[p][ci] = 0.f;
        #pragma unroll 1
        for (int d4 = 0; d4 < 64; ++d4) {
            float4 ev[4];
            #pragma unroll
            for (int ci = 0; ci < 4; ++ci)
                ev[ci] = *(const float4*)(emb + (size_t)(ci * 256 + t) * 256 + d4 * 4);
            #pragma unroll
            for (int p = 0; p < RTILE; ++p) {
                const float4 zv = *(const float4*)(&zl[p][d4 * 4]);
                #pragma unroll
                for (int ci = 0; ci < 4; ++ci) {
                    dot[p][ci] = fmaf(zv.x, ev[ci].x, dot[p][ci]);
                    dot[p][ci] = fmaf(zv.y, ev[ci].y, dot[p][ci]);
                    dot[p][ci] = fmaf(zv.z, ev[ci].z, dot[p][ci]);
                    dot[p][ci] = fmaf(zv.w, ev[ci].w, dot[p][ci]);
                }
            }
        }
        float en[4];
        #pragma unroll
        for (int ci = 0; ci < 4; ++ci) en[ci] = enorm[ci * 256 + t];
        #pragma unroll
        for (int p = 0; p < RTILE; ++p) {
            unsigned long long k = packkey(fmaf(-2.f, dot[p][0], en[0]), t);
            #pragma unroll
            for (int ci = 1; ci < 4; ++ci) {
                const unsigned long long k2 =
                    packkey(fmaf(-2.f, dot[p][ci], en[ci]), ci * 256 + t);
                k = (k2 < k) ? k2 : k;
            }
            atomicMin(&lkey[p], k);
        }
        __syncthreads();
        if (t < RTILE && base + t < n) {
            const int p = rlist[base + t];
            const int fc = (int)(lkey[t] & 0xFFFFFFFFull);
            const int old = idx_out[p];
            if (fc != old) {
                atomicAdd(&counts[old], -1.0f);
                atomicAdd(&counts[fc], 1.0f);
                idx_out[p] = fc;
                idx_out_f[p] = (float)fc;
            }
        }
        __syncthreads();
    }
}

// Fused quantize + dw-segment-sum + loss. Block = one dim d (256 blocks x 512 thr).
__global__ __launch_bounds__(512) void dwq_kernel(
    const float* __restrict__ z, const float* __restrict__ emb,
    const int* __restrict__ idx, const float* __restrict__ ema_emb,
    float* __restrict__ out_q, float* __restrict__ out_ema,
    float* __restrict__ lossp)
{
    __shared__ float kdw[KC];
    __shared__ float ecol[KC];
    __shared__ float red[8];
    const int d = blockIdx.x;
    const int t = threadIdx.x;
    #pragma unroll
    for (int k = t; k < KC; k += 512) { kdw[k] = 0.f; ecol[k] = emb[(size_t)k * 256 + d]; }
    __syncthreads();
    float ls = 0.f;
    #pragma unroll 1
    for (int it = 0; it < 64; ++it) {
        const int e = it * 512 + t;            // float4-unit over (b, hw)
        const int b = e >> 10, hwi = (e & 1023) << 2;
        const size_t zoff = (size_t)b * 1048576 + (size_t)d * 4096 + hwi;
        const float4 zv = *(const float4*)(z + zoff);
        const int4 iv = *(const int4*)(idx + b * 4096 + hwi);
        const float q0 = ecol[iv.x], q1 = ecol[iv.y], q2 = ecol[iv.z], q3 = ecol[iv.w];
        float4 qv; qv.x = q0; qv.y = q1; qv.z = q2; qv.w = q3;
        *(float4*)(out_q + zoff) = qv;
        atomicAdd(&kdw[iv.x], zv.x);
        atomicAdd(&kdw[iv.y], zv.y);
        atomicAdd(&kdw[iv.z], zv.z);
        atomicAdd(&kdw[iv.w], zv.w);
        const float d0 = zv.x - q0, d1 = zv.y - q1, d2 = zv.z - q2, d3 = zv.w - q3;
        ls += (d0 * d0 + d1 * d1) + (d2 * d2 + d3 * d3);
    }
    __syncthreads();
    #pragma unroll
    for (int k = t; k < KC; k += 512)
        out_ema[(size_t)k * 256 + d] = 0.99f * ema_emb[(size_t)k * 256 + d] + 0.01f * kdw[k];
    #pragma unroll
    for (int off = 32; off > 0; off >>= 1) ls += __shfl_down(ls, off);
    if ((t & 63) == 0) red[t >> 6] = ls;
    __syncthreads();
    if (t == 0) {
        float s = 0.f;
        #pragma unroll
        for (int i = 0; i < 8; ++i) s += red[i];
        lossp[blockIdx.x] = s;
    }
}

__global__ __launch_bounds__(256) void finalize_kernel(
    const float* __restrict__ ema_cs, const float* __restrict__ counts,
    const float* __restrict__ lossp, float* __restrict__ out)
{
    const int i = blockIdx.x * 256 + threadIdx.x;   // 4 blocks
    out[OUT_CS + i] = 0.99f * ema_cs[i] + 0.01f * counts[i];
    if (blockIdx.x == 0) {
        float s = lossp[threadIdx.x];
        #pragma unroll
        for (int off = 32; off > 0; off >>= 1) s += __shfl_down(s, off);
        __shared__ float red[4];
        if ((threadIdx.x & 63) == 0) red[threadIdx.x >> 6] = s;
        __syncthreads();
        if (threadIdx.x == 0)
            out[OUT_LOSS] = 0.25f * ((red[0] + red[1]) + (red[2] + red[3])) / 33554432.0f;
    }
}

// ---------- fallback fp32 GEMM (R2 path, used if ws too small) ----------
__global__ __launch_bounds__(256) void dist_argmin_kernel(
    const float* __restrict__ z, const float* __restrict__ emb,
    const float* __restrict__ enorm, int* __restrict__ idx_out,
    float* __restrict__ idx_out_f, float* __restrict__ counts)
{
    __shared__ float smem[4096];
    float* As = smem;
    float* Bs = smem + 1024;
    const int tid = threadIdx.x;
    const int tx = tid & 15, ty = tid >> 4;
    const int p0 = blockIdx.x * 128;
    const int b = p0 >> 12, hw0 = p0 & 4095;
    const float* zb = z + (size_t)b * (DD * HWSZ) + hw0;
    const int arow = (tid & 31) * 4, akd = tid >> 5;
    const int bcode = tid >> 1, bj = (tid & 1) * 4;
    float best[8]; int bidx[8];
    #pragma unroll
    for (int i = 0; i < 8; i++) { best[i] = 3.4e38f; bidx[i] = 0; }
    #pragma unroll 1
    for (int cc = 0; cc < 8; ++cc) {
        const int c0 = cc * 128;
        float acc[8][8];
        #pragma unroll
        for (int i = 0; i < 8; i++)
            #pragma unroll
            for (int j = 0; j < 8; j++) acc[i][j] = 0.0f;
        #pragma unroll 1
        for (int dk = 0; dk < 32; ++dk) {
            const int kk0 = dk * 8;
            const float4 av = *(const float4*)(zb + (kk0 + akd) * HWSZ + arow);
            const float4 bv = *(const float4*)(emb + (c0 + bcode) * DD + kk0 + bj);
            __syncthreads();
            *(float4*)(As + akd * 128 + arow) = av;
            Bs[(bj + 0) * 128 + bcode] = bv.x;
            Bs[(bj + 1) * 128 + bcode] = bv.y;
            Bs[(bj + 2) * 128 + bcode] = bv.z;
            Bs[(bj + 3) * 128 + bcode] = bv.w;
            __syncthreads();
            #pragma unroll
            for (int kk = 0; kk < 8; ++kk) {
                const float4 a0 = *(const float4*)(As + kk * 128 + ty * 8);
                const float4 a1 = *(const float4*)(As + kk * 128 + ty * 8 + 4);
                const float4 b0 = *(const float4*)(Bs + kk * 128 + tx * 8);
                const float4 b1 = *(const float4*)(Bs + kk * 128 + tx * 8 + 4);
                const float a[8] = {a0.x,a0.y,a0.z,a0.w,a1.x,a1.y,a1.z,a1.w};
                const float bb[8] = {b0.x,b0.y,b0.z,b0.w,b1.x,b1.y,b1.z,b1.w};
                #pragma unroll
                for (int i = 0; i < 8; i++)
                    #pragma unroll
                    for (int j = 0; j < 8; j++)
                        acc[i][j] = fmaf(a[i], bb[j], acc[i][j]);
            }
        }
        const float4 en0 = *(const float4*)(enorm + c0 + tx * 8);
        const float4 en1 = *(const float4*)(enorm + c0 + tx * 8 + 4);
        const float en[8] = {en0.x,en0.y,en0.z,en0.w,en1.x,en1.y,en1.z,en1.w};
        #pragma unroll
        for (int j = 0; j < 8; j++) {
            const int c = c0 + tx * 8 + j;
            #pragma unroll
            for (int i = 0; i < 8; i++) {
                const float dist = fmaf(-2.0f, acc[i][j], en[j]);
                if (dist < best[i]) { best[i] = dist; bidx[i] = c; }
            }
        }
    }
    __syncthreads();
    float* rmin = smem;
    int* ridx = (int*)(smem + 2048);
    #pragma unroll
    for (int i = 0; i < 8; i++) {
        const int r = ty * 8 + i;
        rmin[r * 16 + tx] = best[i];
        ridx[r * 16 + tx] = bidx[i];
    }
    __syncthreads();
    if (tid < 128) {
        const int r = tid;
        float m = rmin[r * 16]; int mi = ridx[r * 16];
        #pragma unroll
        for (int tt = 1; tt < 16; tt++) {
            const float v = rmin[r * 16 + tt];
            const int vi = ridx[r * 16 + tt];
            if (v < m || (v == m && vi < mi)) { m = v; mi = vi; }
        }
        const int p = p0 + r;
        idx_out[p] = mi;
        idx_out_f[p] = (float)mi;
        atomicAdd(&counts[mi], 1.0f);
    }
}

extern "C" void kernel_launch(void* const* d_in, const int* in_sizes, int n_in,
                              void* d_out, int out_size, void* d_ws, size_t ws_size,
                              hipStream_t stream) {
    const float* z       = (const float*)d_in[0];
    const float* emb     = (const float*)d_in[1];
    const float* ema_cs  = (const float*)d_in[2];
    const float* ema_emb = (const float*)d_in[3];
    float* out = (float*)d_out;
    float* ws  = (float*)d_ws;

    int*   ws_idx    = (int*)(ws + WS_IDX);
    float* ws_counts = ws + WS_COUNTS;
    int*   ws_rcnt   = (int*)(ws + WS_RCNT);
    float* ws_lossp  = ws + WS_LOSSP;
    float* ws_enorm  = ws + WS_ENORM;
    int*   ws_rlist  = (int*)(ws + WS_RLIST);
    unsigned short* ws_eaug = (unsigned short*)(ws + WS_EAUG);
    unsigned short* ws_zaug = (unsigned short*)(ws + WS_ZAUG);

    // zero counts + rescue counter
    hipMemsetAsync(ws_counts, 0, 1025 * sizeof(float), stream);
    hipLaunchKernelGGL(enorm_kernel, dim3(KC), dim3(256), 0, stream, emb, ws_enorm);

    if (ws_size >= (size_t)WS_NEED_FLOATS * sizeof(float)) {
        hipLaunchKernelGGL(convert_z_kernel, dim3(4096), dim3(256), 0, stream, z, ws_zaug);
        hipLaunchKernelGGL(convert_emb_kernel, dim3(96), dim3(256), 0, stream, emb, ws_eaug);
        hipLaunchKernelGGL(gemm_argmin_kernel, dim3(1024), dim3(512), 0, stream,
                           ws_zaug, ws_eaug, ws_enorm, ws_idx, out + OUT_IDX,
                           ws_counts, ws_rcnt, ws_rlist);
        hipLaunchKernelGGL(rescue_kernel, dim3(512), dim3(256), 0, stream,
                           z, emb, ws_enorm, ws_rcnt, ws_rlist,
                           ws_idx, out + OUT_IDX, ws_counts);
    } else {
        hipLaunchKernelGGL(dist_argmin_kernel, dim3(NP / 128), dim3(256), 0, stream,
                           z, emb, ws_enorm, ws_idx, out + OUT_IDX, ws_counts);
    }

    hipLaunchKernelGGL(dwq_kernel, dim3(DD), dim3(512), 0, stream,
                       z, emb, ws_idx, ema_emb, out, out + OUT_EMA, ws_lossp);
    hipLaunchKernelGGL(finalize_kernel, dim3(4), dim3(256), 0, stream,
                       ema_cs, ws_counts, ws_lossp, out);
}

// Round 6
// 826.839 us; speedup vs baseline: 6.3748x; 1.0441x over previous
//
#include <hip/hip_runtime.h>

// Problem constants
#define KC 1024          // num codes
#define DD 256           // embedding dim
#define NP 131072        // B*H*W points
#define HWSZ 4096        // H*W
#define TOTZ 33554432    // B*D*H*W

// d_out float offsets (tuple concat: quantized, loss, indices, cluster_size, ema_emb)
#define OUT_Q    0
#define OUT_LOSS 33554432
#define OUT_IDX  33554433
#define OUT_CS   33685505
#define OUT_EMA  33686529

// workspace float offsets
#define WS_IDX    0         // int[131072]
#define WS_COUNTS 131072    // float[1024]
#define WS_RCNT   132096    // int[1]  (memset together with counts: 1025 floats)
#define WS_LOSSP  132352    // float[256]
#define WS_ENORM  132608    // float[1024]
#define WS_RLIST  133632    // int[131072]
#define WS_EAUG   264704    // ushort[786432] = 393216 floats (8 cc x 12 ks x 16KB)
#define WS_ZAUG   657920    // ushort[67108864] = 33554432 floats (1024 pt x 8 ksA x 16KB)
#define WS_NEED_FLOATS (WS_ZAUG + 33554432)

#define MARGIN 0.0625f
#define RTILE 16

typedef __attribute__((ext_vector_type(8))) short bf16x8;
typedef __attribute__((ext_vector_type(4))) float f32x4;

__device__ inline unsigned short f2bf_rne(float x) {
    unsigned u = __float_as_uint(x);
    unsigned r = u + 0x7FFFu + ((u >> 16) & 1u);
    return (unsigned short)(r >> 16);
}
__device__ inline float bf2f(unsigned short h) {
    return __uint_as_float(((unsigned)h) << 16);
}
__device__ inline void gl_lds16(const void* g, void* l) {
    __builtin_amdgcn_global_load_lds(
        (const __attribute__((address_space(1))) unsigned int*)g,
        (__attribute__((address_space(3))) unsigned int*)l, 16, 0, 0);
}
// monotone float->uint, packed with code index: min key = min dist, tie -> min idx
__device__ inline unsigned long long packkey(float d, int c) {
    unsigned u = __float_as_uint(d);
    u = (u & 0x80000000u) ? ~u : (u | 0x80000000u);
    return (((unsigned long long)u) << 32) | (unsigned)c;
}

__global__ __launch_bounds__(256) void enorm_kernel(const float* __restrict__ emb,
                                                    float* __restrict__ enorm) {
    const int k = blockIdx.x;
    float v = emb[k * DD + threadIdx.x];
    v *= v;
    #pragma unroll
    for (int off = 32; off > 0; off >>= 1) v += __shfl_down(v, off);
    __shared__ float red[4];
    if ((threadIdx.x & 63) == 0) red[threadIdx.x >> 6] = v;
    __syncthreads();
    if (threadIdx.x == 0) enorm[k] = (red[0] + red[1]) + (red[2] + red[3]);
}

// z_aug: [pt(1024)][ksA(8)][kc(2)][mt(8)][lane(64)][8 bf16]
// ksA 0..3 = hi, 4..7 = mid. Fused: one block computes hi AND mid (z read once).
__global__ __launch_bounds__(256) void convert_z_kernel(
    const float* __restrict__ z, unsigned short* __restrict__ zaug)
{
    const int blk = blockIdx.x;            // pt*4 + kslot
    const int pt = blk >> 2, kslot = blk & 3;
    const int kbase0 = kslot * 64;
    unsigned short* outH = zaug + (size_t)(pt * 8 + kslot) * 8192;
    unsigned short* outM = zaug + (size_t)(pt * 8 + 4 + kslot) * 8192;
    #pragma unroll
    for (int i = 0; i < 4; ++i) {
        const int f = i * 256 + threadIdx.x;   // fragment index [0,1024)
        const int kc = f >> 9, mt = (f >> 6) & 7, lane = f & 63;
        const int q = lane >> 4, col = lane & 15;
        const int p = pt * 128 + mt * 16 + col;
        const int b = p >> 12, hw = p & 4095;
        const int k0 = kbase0 + kc * 32 + q * 8;
        const float* src = z + (size_t)b * 1048576 + (size_t)k0 * 4096 + hw;
        unsigned short vh[8], vm[8];
        #pragma unroll
        for (int j = 0; j < 8; ++j) {
            const float x = src[j * 4096];
            const unsigned short h = f2bf_rne(x);
            vh[j] = h;
            vm[j] = f2bf_rne(x - bf2f(h));
        }
        *(uint4*)(outH + (size_t)f * 8) = *(uint4*)vh;
        *(uint4*)(outM + (size_t)f * 8) = *(uint4*)vm;
    }
}

// emb_aug: [cc(8)][ks(12)][kc(2)][nt(8)][lane(64)][8 bf16]; ks 0..7 = hi, 8..11 = mid
__global__ __launch_bounds__(256) void convert_emb_kernel(
    const float* __restrict__ emb, unsigned short* __restrict__ eaug)
{
    const int blk = blockIdx.x;            // cc*12 + ks
    const int cc = blk / 12, ks = blk % 12;
    const int mode = (ks >= 8);
    unsigned short* outp = eaug + (size_t)blk * 8192;
    #pragma unroll
    for (int i = 0; i < 4; ++i) {
        const int f = i * 256 + threadIdx.x;
        const int kc = f >> 9, nt = (f >> 6) & 7, lane = f & 63;
        const int q = lane >> 4, col = lane & 15;
        const int n = cc * 128 + nt * 16 + col;
        const int k0 = ((ks * 64) & 255) + kc * 32 + q * 8;
        const float* src = emb + (size_t)n * 256 + k0;
        unsigned short v[8];
        #pragma unroll
        for (int j = 0; j < 8; ++j) {
            const float x = src[j];
            const unsigned short h = f2bf_rne(x);
            v[j] = mode ? f2bf_rne(x - bf2f(h)) : h;
        }
        *(uint4*)(outp + (size_t)f * 8) = *(uint4*)v;
    }
}

// MFMA GEMM + fused argmin. Block: 128 points x 1024 codes, 512 threads = 8 waves.
// A (zaug) staged persistently in LDS in two 64KB halves (ksA 0-3 serve ks
// {0-3,8-11}; ksA 4-7 serve ks {4-7}) -> only 16 barriers/block. B (eaug, L2-hot)
// loaded DIRECTLY global->VGPR as fragment-ordered dwordx4 with one-ks-ahead
// register prefetch -> zero barriers in the ks loop (compiler emits fine vmcnt).
// Waves: mh = w&1 (pts half), nq = w>>1 (code quarter of the 256-code group g).
__global__ __launch_bounds__(512) void gemm_argmin_kernel(
    const unsigned short* __restrict__ zaug, const unsigned short* __restrict__ eaug,
    const float* __restrict__ enorm, int* __restrict__ idx_out,
    float* __restrict__ idx_out_f, float* __restrict__ counts,
    int* __restrict__ rcnt, int* __restrict__ rlist)
{
    __shared__ float smem[16384];                      // 64 KB: A slabs, then reduce
    unsigned short* aS = (unsigned short*)smem;        // 4 slabs x 8192 hw
    const int t = threadIdx.x, w = t >> 6, lane = t & 63;
    const int mh = w & 1, nq = w >> 1;
    const int col = lane & 15;
    const int pt = blockIdx.x;

    float rb[16], rs[16]; int ri[16];
    #pragma unroll
    for (int s = 0; s < 16; ++s) { rb[s] = 3.4e38f; rs[s] = 3.4e38f; ri[s] = 0; }

    const unsigned short* zb = zaug + (size_t)pt * 65536;   // halfword units

    #pragma unroll 1
    for (int g = 0; g < 4; ++g) {
        const int ccg = g * 2 + (nq >> 1);
        const int nbase = ccg * 128 + (nq & 1) * 64;
        const unsigned short* eb = eaug + (size_t)ccg * (12 * 8192)
                                 + (nq & 1) * 2048 + (size_t)lane * 8;
        f32x4 acc[4][4];
        #pragma unroll
        for (int mi = 0; mi < 4; ++mi)
            #pragma unroll
            for (int ni = 0; ni < 4; ++ni) acc[mi][ni] = (f32x4){0.f, 0.f, 0.f, 0.f};
        float en[4];
        #pragma unroll
        for (int ni = 0; ni < 4; ++ni) en[ni] = enorm[nbase + ni * 16 + col];

        #pragma unroll 1
        for (int ph = 0; ph < 2; ++ph) {
            __syncthreads();                       // prior reads of aS done
            #pragma unroll
            for (int i = 0; i < 8; ++i) {
                const int off = i * 4096 + w * 512 + lane * 8;
                gl_lds16(zb + ph * 32768 + off, aS + off);
            }
            __syncthreads();                       // staging complete
            const int nks = ph ? 4 : 8;
            bf16x8 bcur[2][4], bnxt[2][4];
            {
                const unsigned short* ebk = eb + (size_t)(ph ? 4 : 0) * 8192;
                #pragma unroll
                for (int kc = 0; kc < 2; ++kc)
                    #pragma unroll
                    for (int ni = 0; ni < 4; ++ni)
                        bcur[kc][ni] = *(const bf16x8*)(ebk + kc * 4096 + ni * 512);
            }
            #pragma unroll 1
            for (int j = 0; j < nks; ++j) {
                const int slab = j & 3;
                if (j + 1 < nks) {
                    const int jn = j + 1;
                    const int ksn = ph ? (4 + jn) : ((jn < 4) ? jn : jn + 4);
                    const unsigned short* ebk = eb + (size_t)ksn * 8192;
                    #pragma unroll
                    for (int kc = 0; kc < 2; ++kc)
                        #pragma unroll
                        for (int ni = 0; ni < 4; ++ni)
                            bnxt[kc][ni] = *(const bf16x8*)(ebk + kc * 4096 + ni * 512);
                }
                #pragma unroll
                for (int kc = 0; kc < 2; ++kc) {
                    bf16x8 af[4];
                    #pragma unroll
                    for (int mi = 0; mi < 4; ++mi)
                        af[mi] = *(const bf16x8*)(aS + slab * 8192 + kc * 4096
                                                  + (mh * 4 + mi) * 512 + lane * 8);
                    #pragma unroll
                    for (int mi = 0; mi < 4; ++mi)
                        #pragma unroll
                        for (int ni = 0; ni < 4; ++ni)
                            acc[mi][ni] = __builtin_amdgcn_mfma_f32_16x16x32_bf16(
                                af[mi], bcur[kc][ni], acc[mi][ni], 0, 0, 0);
                }
                #pragma unroll
                for (int kc = 0; kc < 2; ++kc)
                    #pragma unroll
                    for (int ni = 0; ni < 4; ++ni)
                        bcur[kc][ni] = bnxt[kc][ni];
            }
        }
        // epilogue: dist = enorm - 2*dot; per-slot (min, 2nd, idx) over 4 ni, merge
        #pragma unroll
        for (int mi = 0; mi < 4; ++mi) {
            #pragma unroll
            for (int r = 0; r < 4; ++r) {
                const int s = mi * 4 + r;
                float v0 = fmaf(-2.f, acc[mi][0][r], en[0]);
                float v1 = fmaf(-2.f, acc[mi][1][r], en[1]);
                float v2 = fmaf(-2.f, acc[mi][2][r], en[2]);
                float v3 = fmaf(-2.f, acc[mi][3][r], en[3]);
                const int nb = nbase + col;
                float b01 = fminf(v0, v1), x01 = fmaxf(v0, v1);
                int   i01 = (v1 < v0) ? nb + 16 : nb;
                float b23 = fminf(v2, v3), x23 = fmaxf(v2, v3);
                int   i23 = (v3 < v2) ? nb + 48 : nb + 32;
                float b = fminf(b01, b23);
                int   ib = (b23 < b01) ? i23 : i01;
                float s2 = fminf(fmaxf(b01, b23), fminf(x01, x23));
                if (b < rb[s]) { rs[s] = fminf(rb[s], s2); rb[s] = b; ri[s] = ib; }
                else           { rs[s] = fminf(rs[s], b); }
            }
        }
    }

    // two-phase dump (mh=0 then mh=1; 4 waves x 16 slots x 64 lanes = 48KB),
    // threads 0..63 finalize one point row each per phase.
    float* rbS = smem;                 // [4][16][64]
    float* rsS = smem + 4096;
    int*   riS = (int*)(smem + 8192);
    #pragma unroll 1
    for (int ph = 0; ph < 2; ++ph) {
        __syncthreads();
        if (mh == ph) {
            #pragma unroll
            for (int s = 0; s < 16; ++s) {
                rbS[nq * 1024 + s * 64 + lane] = rb[s];
                rsS[nq * 1024 + s * 64 + lane] = rs[s];
                riS[nq * 1024 + s * 64 + lane] = ri[s];
            }
        }
        __syncthreads();
        if (t < 64) {
            const int r = t;
            const int mi = r >> 4, q = (r >> 2) & 3, rr = r & 3;
            const int s = mi * 4 + rr;
            float B = 3.4e38f, S = 3.4e38f; int I = 0;
            #pragma unroll
            for (int wv = 0; wv < 4; ++wv) {
                const int base = wv * 1024 + s * 64 + q * 16;
                #pragma unroll
                for (int ln = 0; ln < 16; ++ln) {
                    const float b = rbS[base + ln];
                    const float s2 = rsS[base + ln];
                    const int   i = riS[base + ln];
                    if (b < B) { S = fminf(B, s2); B = b; I = i; }
                    else       { S = fminf(S, b); }
                }
            }
            const int p = pt * 128 + ph * 64 + r;
            idx_out[p] = I;
            idx_out_f[p] = (float)I;
            atomicAdd(&counts[I], 1.0f);
            if (S - B < MARGIN) {
                const int pos = atomicAdd(rcnt, 1);
                rlist[pos] = p;
            }
        }
    }
}

// Batched exact fp32 re-argmin: 16 points staged in LDS, each thread owns 4
// codes (c = ci*256 + t) with dot[16][4] register accumulators -> per d4 only
// 16 LDS reads + 4 e-loads for 256 FMA. Numerics identical to prior version.
__global__ __launch_bounds__(256) void rescue_kernel(
    const float* __restrict__ z, const float* __restrict__ emb,
    const float* __restrict__ enorm, const int* __restrict__ rcnt,
    const int* __restrict__ rlist, int* __restrict__ idx_out,
    float* __restrict__ idx_out_f, float* __restrict__ counts)
{
    __shared__ float zl[RTILE][DD];
    __shared__ unsigned long long lkey[RTILE];
    const int n = *rcnt;
    if (n <= 0) return;
    const int ntiles = (n + RTILE - 1) / RTILE;
    const int t = threadIdx.x;
    const int slot = t & 15, drow = t >> 4;    // thread loads 16 dims for one slot
    #pragma unroll 1
    for (int tile = blockIdx.x; tile < ntiles; tile += gridDim.x) {
        const int base = tile * RTILE;
        {
            const int ridx = min(base + slot, n - 1);   // clamp: dup compute, guarded update
            const int p = rlist[ridx];
            const int b = p >> 12, hw = p & 4095;
            const float* zp = z + (size_t)b * 1048576 + hw;
            #pragma unroll
            for (int j = 0; j < 16; ++j)
                zl[slot][drow * 16 + j] = zp[(size_t)(drow * 16 + j) * 4096];
        }
        if (t < RTILE) lkey[t] = ~0ull;
        __syncthreads();
        float dot[RTILE][4];
        #pragma unroll
        for (int p = 0; p < RTILE; ++p)
            #pragma unroll
            for (int ci = 0; ci < 4; ++ci) dot[p][ci] = 0.f;
        #pragma unroll 1
        for (int d4 = 0; d4 < 64; ++d4) {
            float4 ev[4];
            #pragma unroll
            for (int ci = 0; ci < 4; ++ci)
                ev[ci] = *(const float4*)(emb + (size_t)(ci * 256 + t) * 256 + d4 * 4);
            #pragma unroll
            for (int p = 0; p < RTILE; ++p) {
                const float4 zv = *(const float4*)(&zl[p][d4 * 4]);
                #pragma unroll
                for (int ci = 0; ci < 4; ++ci) {
                    dot[p][ci] = fmaf(zv.x, ev[ci].x, dot[p][ci]);
                    dot[p][ci] = fmaf(zv.y, ev[ci].y, dot[p][ci]);
                    dot[p][ci] = fmaf(zv.z, ev[ci].z, dot[p][ci]);
                    dot[p][ci] = fmaf(zv.w, ev[ci].w, dot[p][ci]);
                }
            }
        }
        float en[4];
        #pragma unroll
        for (int ci = 0; ci < 4; ++ci) en[ci] = enorm[ci * 256 + t];
        #pragma unroll
        for (int p = 0; p < RTILE; ++p) {
            unsigned long long k = packkey(fmaf(-2.f, dot[p][0], en[0]), t);
            #pragma unroll
            for (int ci = 1; ci < 4; ++ci) {
                const unsigned long long k2 =
                    packkey(fmaf(-2.f, dot[p][ci], en[ci]), ci * 256 + t);
                k = (k2 < k) ? k2 : k;
            }
            atomicMin(&lkey[p], k);
        }
        __syncthreads();
        if (t < RTILE && base + t < n) {
            const int p = rlist[base + t];
            const int fc = (int)(lkey[t] & 0xFFFFFFFFull);
            const int old = idx_out[p];
            if (fc != old) {
                atomicAdd(&counts[old], -1.0f);
                atomicAdd(&counts[fc], 1.0f);
                idx_out[p] = fc;
                idx_out_f[p] = (float)fc;
            }
        }
        __syncthreads();
    }
}

// Fused quantize + dw-segment-sum + loss. Block = one dim d (256 blocks x 512 thr).
__global__ __launch_bounds__(512) void dwq_kernel(
    const float* __restrict__ z, const float* __restrict__ emb,
    const int* __restrict__ idx, const float* __restrict__ ema_emb,
    float* __restrict__ out_q, float* __restrict__ out_ema,
    float* __restrict__ lossp)
{
    __shared__ float kdw[KC];
    __shared__ float ecol[KC];
    __shared__ float red[8];
    const int d = blockIdx.x;
    const int t = threadIdx.x;
    #pragma unroll
    for (int k = t; k < KC; k += 512) { kdw[k] = 0.f; ecol[k] = emb[(size_t)k * 256 + d]; }
    __syncthreads();
    float ls = 0.f;
    #pragma unroll 1
    for (int it = 0; it < 64; ++it) {
        const int e = it * 512 + t;            // float4-unit over (b, hw)
        const int b = e >> 10, hwi = (e & 1023) << 2;
        const size_t zoff = (size_t)b * 1048576 + (size_t)d * 4096 + hwi;
        const float4 zv = *(const float4*)(z + zoff);
        const int4 iv = *(const int4*)(idx + b * 4096 + hwi);
        const float q0 = ecol[iv.x], q1 = ecol[iv.y], q2 = ecol[iv.z], q3 = ecol[iv.w];
        float4 qv; qv.x = q0; qv.y = q1; qv.z = q2; qv.w = q3;
        *(float4*)(out_q + zoff) = qv;
        atomicAdd(&kdw[iv.x], zv.x);
        atomicAdd(&kdw[iv.y], zv.y);
        atomicAdd(&kdw[iv.z], zv.z);
        atomicAdd(&kdw[iv.w], zv.w);
        const float d0 = zv.x - q0, d1 = zv.y - q1, d2 = zv.z - q2, d3 = zv.w - q3;
        ls += (d0 * d0 + d1 * d1) + (d2 * d2 + d3 * d3);
    }
    __syncthreads();
    #pragma unroll
    for (int k = t; k < KC; k += 512)
        out_ema[(size_t)k * 256 + d] = 0.99f * ema_emb[(size_t)k * 256 + d] + 0.01f * kdw[k];
    #pragma unroll
    for (int off = 32; off > 0; off >>= 1) ls += __shfl_down(ls, off);
    if ((t & 63) == 0) red[t >> 6] = ls;
    __syncthreads();
    if (t == 0) {
        float s = 0.f;
        #pragma unroll
        for (int i = 0; i < 8; ++i) s += red[i];
        lossp[blockIdx.x] = s;
    }
}

__global__ __launch_bounds__(256) void finalize_kernel(
    const float* __restrict__ ema_cs, const float* __restrict__ counts,
    const float* __restrict__ lossp, float* __restrict__ out)
{
    const int i = blockIdx.x * 256 + threadIdx.x;   // 4 blocks
    out[OUT_CS + i] = 0.99f * ema_cs[i] + 0.01f * counts[i];
    if (blockIdx.x == 0) {
        float s = lossp[threadIdx.x];
        #pragma unroll
        for (int off = 32; off > 0; off >>= 1) s += __shfl_down(s, off);
        __shared__ float red[4];
        if ((threadIdx.x & 63) == 0) red[threadIdx.x >> 6] = s;
        __syncthreads();
        if (threadIdx.x == 0)
            out[OUT_LOSS] = 0.25f * ((red[0] + red[1]) + (red[2] + red[3])) / 33554432.0f;
    }
}

// ---------- fallback fp32 GEMM (R2 path, used if ws too small) ----------
__global__ __launch_bounds__(256) void dist_argmin_kernel(
    const float* __restrict__ z, const float* __restrict__ emb,
    const float* __restrict__ enorm, int* __restrict__ idx_out,
    float* __restrict__ idx_out_f, float* __restrict__ counts)
{
    __shared__ float smem[4096];
    float* As = smem;
    float* Bs = smem + 1024;
    const int tid = threadIdx.x;
    const int tx = tid & 15, ty = tid >> 4;
    const int p0 = blockIdx.x * 128;
    const int b = p0 >> 12, hw0 = p0 & 4095;
    const float* zb = z + (size_t)b * (DD * HWSZ) + hw0;
    const int arow = (tid & 31) * 4, akd = tid >> 5;
    const int bcode = tid >> 1, bj = (tid & 1) * 4;
    float best[8]; int bidx[8];
    #pragma unroll
    for (int i = 0; i < 8; i++) { best[i] = 3.4e38f; bidx[i] = 0; }
    #pragma unroll 1
    for (int cc = 0; cc < 8; ++cc) {
        const int c0 = cc * 128;
        float acc[8][8];
        #pragma unroll
        for (int i = 0; i < 8; i++)
            #pragma unroll
            for (int j = 0; j < 8; j++) acc[i][j] = 0.0f;
        #pragma unroll 1
        for (int dk = 0; dk < 32; ++dk) {
            const int kk0 = dk * 8;
            const float4 av = *(const float4*)(zb + (kk0 + akd) * HWSZ + arow);
            const float4 bv = *(const float4*)(emb + (c0 + bcode) * DD + kk0 + bj);
            __syncthreads();
            *(float4*)(As + akd * 128 + arow) = av;
            Bs[(bj + 0) * 128 + bcode] = bv.x;
            Bs[(bj + 1) * 128 + bcode] = bv.y;
            Bs[(bj + 2) * 128 + bcode] = bv.z;
            Bs[(bj + 3) * 128 + bcode] = bv.w;
            __syncthreads();
            #pragma unroll
            for (int kk = 0; kk < 8; ++kk) {
                const float4 a0 = *(const float4*)(As + kk * 128 + ty * 8);
                const float4 a1 = *(const float4*)(As + kk * 128 + ty * 8 + 4);
                const float4 b0 = *(const float4*)(Bs + kk * 128 + tx * 8);
                const float4 b1 = *(const float4*)(Bs + kk * 128 + tx * 8 + 4);
                const float a[8] = {a0.x,a0.y,a0.z,a0.w,a1.x,a1.y,a1.z,a1.w};
                const float bb[8] = {b0.x,b0.y,b0.z,b0.w,b1.x,b1.y,b1.z,b1.w};
                #pragma unroll
                for (int i = 0; i < 8; i++)
                    #pragma unroll
                    for (int j = 0; j < 8; j++)
                        acc[i][j] = fmaf(a[i], bb[j], acc[i][j]);
            }
        }
        const float4 en0 = *(const float4*)(enorm + c0 + tx * 8);
        const float4 en1 = *(const float4*)(enorm + c0 + tx * 8 + 4);
        const float en[8] = {en0.x,en0.y,en0.z,en0.w,en1.x,en1.y,en1.z,en1.w};
        #pragma unroll
        for (int j = 0; j < 8; j++) {
            const int c = c0 + tx * 8 + j;
            #pragma unroll
            for (int i = 0; i < 8; i++) {
                const float dist = fmaf(-2.0f, acc[i][j], en[j]);
                if (dist < best[i]) { best[i] = dist; bidx[i] = c; }
            }
        }
    }
    __syncthreads();
    float* rmin = smem;
    int* ridx = (int*)(smem + 2048);
    #pragma unroll
    for (int i = 0; i < 8; i++) {
        const int r = ty * 8 + i;
        rmin[r * 16 + tx] = best[i];
        ridx[r * 16 + tx] = bidx[i];
    }
    __syncthreads();
    if (tid < 128) {
        const int r = tid;
        float m = rmin[r * 16]; int mi = ridx[r * 16];
        #pragma unroll
        for (int tt = 1; tt < 16; tt++) {
            const float v = rmin[r * 16 + tt];
            const int vi = ridx[r * 16 + tt];
            if (v < m || (v == m && vi < mi)) { m = v; mi = vi; }
        }
        const int p = p0 + r;
        idx_out[p] = mi;
        idx_out_f[p] = (float)mi;
        atomicAdd(&counts[mi], 1.0f);
    }
}

extern "C" void kernel_launch(void* const* d_in, const int* in_sizes, int n_in,
                              void* d_out, int out_size, void* d_ws, size_t ws_size,
                              hipStream_t stream) {
    const float* z       = (const float*)d_in[0];
    const float* emb     = (const float*)d_in[1];
    const float* ema_cs  = (const float*)d_in[2];
    const float* ema_emb = (const float*)d_in[3];
    float* out = (float*)d_out;
    float* ws  = (float*)d_ws;

    int*   ws_idx    = (int*)(ws + WS_IDX);
    float* ws_counts = ws + WS_COUNTS;
    int*   ws_rcnt   = (int*)(ws + WS_RCNT);
    float* ws_lossp  = ws + WS_LOSSP;
    float* ws_enorm  = ws + WS_ENORM;
    int*   ws_rlist  = (int*)(ws + WS_RLIST);
    unsigned short* ws_eaug = (unsigned short*)(ws + WS_EAUG);
    unsigned short* ws_zaug = (unsigned short*)(ws + WS_ZAUG);

    // zero counts + rescue counter
    hipMemsetAsync(ws_counts, 0, 1025 * sizeof(float), stream);
    hipLaunchKernelGGL(enorm_kernel, dim3(KC), dim3(256), 0, stream, emb, ws_enorm);

    if (ws_size >= (size_t)WS_NEED_FLOATS * sizeof(float)) {
        hipLaunchKernelGGL(convert_z_kernel, dim3(4096), dim3(256), 0, stream, z, ws_zaug);
        hipLaunchKernelGGL(convert_emb_kernel, dim3(96), dim3(256), 0, stream, emb, ws_eaug);
        hipLaunchKernelGGL(gemm_argmin_kernel, dim3(1024), dim3(512), 0, stream,
                           ws_zaug, ws_eaug, ws_enorm, ws_idx, out + OUT_IDX,
                           ws_counts, ws_rcnt, ws_rlist);
        hipLaunchKernelGGL(rescue_kernel, dim3(512), dim3(256), 0, stream,
                           z, emb, ws_enorm, ws_rcnt, ws_rlist,
                           ws_idx, out + OUT_IDX, ws_counts);
    } else {
        hipLaunchKernelGGL(dist_argmin_kernel, dim3(NP / 128), dim3(256), 0, stream,
                           z, emb, ws_enorm, ws_idx, out + OUT_IDX, ws_counts);
    }

    hipLaunchKernelGGL(dwq_kernel, dim3(DD), dim3(512), 0, stream,
                       z, emb, ws_idx, ema_emb, out, out + OUT_EMA, ws_lossp);
    hipLaunchKernelGGL(finalize_kernel, dim3(4), dim3(256), 0, stream,
                       ema_cs, ws_counts, ws_lossp, out);
}